// Round 2
// baseline (3661.198 us; speedup 1.0000x reference)
//
#include <hip/hip_runtime.h>
#include <hip/hip_bf16.h>

typedef __hip_bfloat16 bf16;
typedef __attribute__((ext_vector_type(8))) short s16x8;
typedef __attribute__((ext_vector_type(4))) float f32x4;

// Problem constants
#define TT 55
#define BB 512
#define CC 512
#define DD 512
#define KK 64
#define NCH 4                    // steps per x-precompute chunk (power of 2)
#define NXS 8                    // x-ring slots (ping-pong of NCH)
#define NHS 8                    // Hall ring slots
#define LDH ((long)NHS*1536)     // Hall ring row stride
#define XW 6400L                 // XGR row width

typedef const __attribute__((address_space(1))) unsigned int gu32;
typedef __attribute__((address_space(3))) unsigned int lu32;
__device__ __forceinline__ void gload16(const void* g, void* l) {
  __builtin_amdgcn_global_load_lds((gu32*)g, (lu32*)l, 16, 0, 0);
}

struct Seg {
  void*  dst;          // destination base (float* or bf16* per mode)
  long   ldd;          // row stride (elements)
  int    col_begin;    // inclusive (GEMM N space), 64-aligned, sorted asc
  int    mode;         // 0 = f32 store (+bias), 1 = f32 +=, 2 = bf16 store (+bias)
  const float* bias;   // indexed by (col - col_begin), may be null
};
struct SegList { Seg s[8]; int n; };

struct GDesc {
  const bf16* A; const bf16* B;
  long lda, ldb;
  int mtiles, ntiles, tile_beg, order, K;  // order: 0=nt-fast, 1=mt-fast, 2=banded(32 mt x all nt)
  SegList segs;
};
struct GArgs { GDesc g[6]; int ng; int total; int chunk; };

// ---------------- batched GEMM: C[seg] (+)= A[MxK] * B^T[NxK], bf16 in, fp32 acc
// 64x128 tile (MxN), BK=64, 4 waves (2x2 of 32x64).
// K-loop is depth-2 software-pipelined: 3 LDS buffer sets, stage K-step k+2 while
// computing k, counted s_waitcnt vmcnt(6) + raw s_barrier (never a full drain in
// the steady state). LDS layout XOR-swizzled (block p of row r holds global block
// p^(r&7)) to kill ds_read_b128 bank conflicts.
__global__ __launch_bounds__(256) void gemm_batched(GArgs args)
{
  __shared__ __align__(16) bf16 As[3][64][64];    // 3 x 8 KB
  __shared__ __align__(16) bf16 Bs[3][128][64];   // 3 x 16 KB

  // XCD-aware: bid%8 ~ XCD; each XCD gets a contiguous tile chunk.
  int tile = (int)(blockIdx.x & 7) * args.chunk + (int)(blockIdx.x >> 3);
  if (tile >= args.total) return;

  int gi = 0;
  for (int i = 1; i < args.ng; ++i) if (tile >= args.g[i].tile_beg) gi = i;
  const GDesc& g = args.g[gi];
  const int local = tile - g.tile_beg;
  int mt, nt;
  if (g.order == 1)      { mt = local % g.mtiles; nt = local / g.mtiles; }
  else if (g.order == 2) { int band = local / (32*g.ntiles); int rem = local % (32*g.ntiles);
                           nt = rem % g.ntiles; mt = band*32 + rem / g.ntiles; }
  else                   { nt = local % g.ntiles; mt = local / g.ntiles; }

  const int tid  = threadIdx.x;
  const int wave = tid >> 6, lane = tid & 63;
  const int q = lane >> 4, mm = lane & 15;
  const int s7 = mm & 7;
  const int wm = wave >> 1, wn = wave & 1;
  const long m0 = (long)mt * 64;
  const long n0 = (long)nt * 128;

  const bf16* Ab = g.A + m0 * g.lda;
  const bf16* Bb = g.B + n0 * g.ldb;
  const long lda = g.lda, ldb = g.ldb;
  const int l8 = lane >> 3;                 // row within 8-row staging group
  const int gc = ((lane & 7) ^ l8) << 3;    // swizzled global col (elements)

  const int nk = g.K >> 6;                  // K-steps (>= 8 for all groups)

  auto stage = [&](int b, int k0) {
#pragma unroll
    for (int p = 0; p < 2; ++p) {
      int r = p*32 + wave*8;
      gload16(Ab + (long)(r + l8)*lda + k0 + gc, &As[b][r][0]);
    }
#pragma unroll
    for (int p = 0; p < 4; ++p) {
      int r = p*32 + wave*8;
      gload16(Bb + (long)(r + l8)*ldb + k0 + gc, &Bs[b][r][0]);
    }
  };

  f32x4 acc[2][4] = {};

  // prologue: 2 K-steps in flight (12 outstanding VMEM per wave)
  stage(0, 0);
  stage(1, 64);
  int cur = 0, stg = 2;

  for (int k = 0; k < nk; ++k) {
    // wait for K-step k's 6 loads (k+1's 6 stay in flight); full drain only on last
    if (k + 1 < nk) asm volatile("s_waitcnt vmcnt(6)" ::: "memory");
    else            asm volatile("s_waitcnt vmcnt(0)" ::: "memory");
    __builtin_amdgcn_s_barrier();   // all waves' k-loads landed; buffer stg free
    if (k + 2 < nk) stage(stg, (k + 2) << 6);
#pragma unroll
    for (int kk = 0; kk < 64; kk += 32) {
      const int pc = ((((kk >> 3) + q) ^ s7) << 3);  // physical col of logical kk+q*8
      s16x8 av[2], bv[4];
#pragma unroll
      for (int i = 0; i < 2; ++i) av[i] = *(const s16x8*)&As[cur][wm*32 + i*16 + mm][pc];
#pragma unroll
      for (int j = 0; j < 4; ++j) bv[j] = *(const s16x8*)&Bs[cur][wn*64 + j*16 + mm][pc];
#pragma unroll
      for (int i = 0; i < 2; ++i)
#pragma unroll
        for (int j = 0; j < 4; ++j)
          acc[i][j] = __builtin_amdgcn_mfma_f32_16x16x32_bf16(av[i], bv[j], acc[i][j], 0,0,0);
    }
    cur = (cur == 2) ? 0 : cur + 1;
    stg = (stg == 2) ? 0 : stg + 1;
  }

  // epilogue: segment lookup per 16-col group (boundaries are 64-aligned)
#pragma unroll
  for (int j = 0; j < 4; ++j) {
    int colbase = (int)n0 + wn*64 + j*16;
    Seg sg = g.segs.s[0];
    for (int i = 1; i < g.segs.n; ++i)
      if (colbase >= g.segs.s[i].col_begin) sg = g.segs.s[i];
    int dcol = colbase + mm - sg.col_begin;
    float bv = sg.bias ? sg.bias[dcol] : 0.0f;
#pragma unroll
    for (int i = 0; i < 2; ++i) {
      f32x4 a = acc[i][j];
#pragma unroll
      for (int r = 0; r < 4; ++r) {
        long row = m0 + wm*32 + i*16 + q*4 + r;  // C/D: col=lane&15, row=q*4+reg
        long off = row * sg.ldd + dcol;
        if (sg.mode == 1)      ((float*)sg.dst)[off] += a[r];
        else if (sg.mode == 2) ((bf16*)sg.dst)[off] = __float2bfloat16(a[r] + bv);
        else                   ((float*)sg.dst)[off] = a[r] + bv;
      }
    }
  }
}

// ---------------- batched cell update: up to 3 independent (step,layer) cells
struct CellDesc {
  const void* xg;      // x-driven gate part (row stride XW), fp32 or bf16 per xbf
  const void* xr;      // x-driven gr part (row stride XW)
  int xbf;             // 1 = xg/xr are bf16, 0 = fp32
  const float* gate;   // fp32 ring [512][2048]
  const float* gate2;  // extra addend (whb ring), may be null
  const float* gate3;  // extra addend (g2b ring), may be null
  const float* gr;     // fp32 [512][64], may be null
  const float* u0;     // may be null
  const float* u1;     // may be null
  float* c;            // [512][512]
  float* d;            // [512][64]
  bf16*  hout;         // row stride LDH
};
struct CArgs { CellDesc e[3]; int n; };

__device__ inline float sigm(float x){ return 1.0f/(1.0f + __expf(-x)); }
__device__ inline float ftanh(float x){ float e = __expf(2.0f*x); return 1.0f - 2.0f/(e + 1.0f); }

// 2 batch rows per block, grid (256, n).
__global__ __launch_bounds__(256) void cell_batched(CArgs a, const float* __restrict__ wd)
{
  const CellDesc e = a.e[blockIdx.y];
  const int tid = threadIdx.x;
  const int r0 = blockIdx.x * 2;
  __shared__ float dn[2][64];

  if (tid < 128) {
    int r = tid >> 6, k = tid & 63;
    long row = r0 + r;
    float gv = e.xbf ? __bfloat162float(((const bf16*)e.xr)[row*XW + k])
                     : ((const float*)e.xr)[row*XW + k];
    if (e.gr) gv += e.gr[row*64 + k];
    if (e.u0) gv += (1.0f/3.0f)*e.u0[row*64 + k];
    if (e.u1) gv += (1.0f/3.0f)*e.u1[row*64 + k];
    float rr = sigm(gv);
    float dv = rr * e.d[row*64 + k];
    e.d[row*64 + k] = dv;
    dn[r][k] = dv;
  }
  __syncthreads();

  float accv[2][2] = {};
#pragma unroll 4
  for (int k = 0; k < 64; ++k) {
    float w0 = wd[k*512 + tid];
    float w1 = wd[k*512 + tid + 256];
#pragma unroll
    for (int r = 0; r < 2; ++r) {
      float dv = dn[r][k];
      accv[0][r] += dv * w0;
      accv[1][r] += dv * w1;
    }
  }

#pragma unroll
  for (int half = 0; half < 2; ++half) {
    int n = tid + half*256;
#pragma unroll
    for (int r = 0; r < 2; ++r) {
      long row = r0 + r;
      const float* gg = e.gate + row*2048;
      float fv = gg[n], iv = gg[512+n], ov = gg[1024+n], cb = gg[1536+n];
      if (e.gate2) {
        const float* g2 = e.gate2 + row*2048;
        fv += g2[n]; iv += g2[512+n]; ov += g2[1024+n]; cb += g2[1536+n];
      }
      if (e.gate3) {
        const float* g3 = e.gate3 + row*2048;
        fv += g3[n]; iv += g3[512+n]; ov += g3[1024+n]; cb += g3[1536+n];
      }
      if (e.xbf) {
        const bf16* xg = (const bf16*)e.xg + row*XW;
        fv += __bfloat162float(xg[n]);      iv += __bfloat162float(xg[512+n]);
        ov += __bfloat162float(xg[1024+n]); cb += __bfloat162float(xg[1536+n]);
      } else {
        const float* xg = (const float*)e.xg + row*XW;
        fv += xg[n]; iv += xg[512+n]; ov += xg[1024+n]; cb += xg[1536+n];
      }
      fv = sigm(fv); iv = sigm(iv); ov = sigm(ov); cb = ftanh(cb);
      float cv = fv * e.c[row*512 + n] + iv * cb + ftanh(accv[half][r]);
      e.c[row*512 + n] = cv;
      e.hout[row*LDH + n] = __float2bfloat16(ov * ftanh(cv));
    }
  }
}

// ---------------- setup kernels
__global__ void k_tpose(const float* __restrict__ src, long srow,
                        bf16* __restrict__ dst, int K, long total)
{
  long idx = (long)blockIdx.x * 256 + threadIdx.x;
  if (idx >= total) return;
  long n = idx / K;
  long k = idx - n * K;
  dst[idx] = __float2bfloat16(src[k * srow + n]);
}

__global__ void k_xconv(const float* __restrict__ x, bf16* __restrict__ xb)
{
  long i = (long)blockIdx.x * 256 + threadIdx.x;
  if (i >= (long)TT*BB*CC) return;
  int cc = (int)(i & 511);
  long r = i >> 9;
  int t = (int)(r / BB), b = (int)(r - (long)t*BB);
  xb[i] = __float2bfloat16(x[((long)b*TT + t)*CC + cc]);
}

__global__ void k_bias(const float* b0,const float* b1,const float* b2,
                       const float* b3,const float* b4,const float* b5,
                       float* out)
{
  int i = blockIdx.x*256 + threadIdx.x;
  if (i < 2048)      out[i] = b0[i] + b1[i];
  else if (i < 4096) out[i] = b2[i-2048] + b3[i-2048];
  else if (i < 6144) out[i] = b4[i-4096] + b5[i-4096];
}

__global__ void k_dinit(const float* __restrict__ keys, float* __restrict__ d)
{
  int i = blockIdx.x*256 + threadIdx.x;
  if (i < 3*BB*KK) d[i] = keys[i % (BB*KK)];
}

// ---------------- host
extern "C" void kernel_launch(void* const* d_in, const int* in_sizes, int n_in,
                              void* d_out, int out_size, void* d_ws, size_t ws_size,
                              hipStream_t stream)
{
  const float* inputs    = (const float*)d_in[0];
  const float* init_keys = (const float*)d_in[1];
  const float* wx_w[3] = {(const float*)d_in[2],  (const float*)d_in[8],  (const float*)d_in[14]};
  const float* wx_b[3] = {(const float*)d_in[3],  (const float*)d_in[9],  (const float*)d_in[15]};
  const float* wh_w[3] = {(const float*)d_in[4],  (const float*)d_in[10], (const float*)d_in[16]};
  const float* wh_b[3] = {(const float*)d_in[5],  (const float*)d_in[11], (const float*)d_in[17]};
  const float* wr_w[3] = {(const float*)d_in[6],  (const float*)d_in[12], (const float*)d_in[18]};
  const float* wl_w[3] = {(const float*)d_in[7],  (const float*)d_in[13], (const float*)d_in[19]};
  const float* wd_w   = (const float*)d_in[20];
  const float* proj_w = (const float*)d_in[21];
  const float* proj_b = (const float*)d_in[22];
  float* out = (float*)d_out;

  char* wsp = (char*)d_ws;
  size_t used = 0;
  auto alloc = [&](size_t bytes) {
    char* p = wsp + used;
    used += (bytes + 255) & ~(size_t)255;
    return p;
  };
  bf16* xb    = (bf16*)alloc((size_t)TT*BB*CC*2);        // [t][b][c] = [28160][512]
  bf16* BXT   = (bf16*)alloc((size_t)6400*512*2);        // x-driven  B^T (padded)
  bf16* BG0T  = (bf16*)alloc((size_t)6400*512*2);        // h0-driven B^T (padded)
  bf16* BG1T  = (bf16*)alloc((size_t)4352*512*2);        // h1-driven B^T (padded)
  bf16* BG2T  = (bf16*)alloc((size_t)2048*512*2);        // h2-driven B^T
  bf16* projT = (bf16*)alloc((size_t)512*1536*2);
  bf16* HallR = (bf16*)alloc((size_t)BB*NHS*1536*2);     // h ring [b][slot][3*512]
  float* accg = (float*)alloc((size_t)4*3*BB*2048*4);    // [slot][l][b][2048]
  float* accr = (float*)alloc((size_t)4*3*BB*64*4);      // [slot][l][b][64]
  float* ubuf = (float*)alloc((size_t)4*2*BB*64*4);      // [slot][j][b][64]
  float* whb1 = (float*)alloc((size_t)2*BB*2048*4);      // Wh1*h1 ring
  float* whb2 = (float*)alloc((size_t)2*BB*2048*4);      // Wh2*h2 ring
  float* g2b  = (float*)alloc((size_t)2*BB*2048*4);      // Wx2[h1-part]*h1 ring (no RMW)
  float* cbuf = (float*)alloc((size_t)3*BB*DD*4);
  float* dbuf = (float*)alloc((size_t)3*BB*KK*4);
  float* biasg= (float*)alloc((size_t)3*2048*4);
  float* dump = (float*)alloc((size_t)BB*128*4);         // pad-column sink

  // x-ring: ping-pong of NCH steps; fp32 if it fits, else bf16
  const size_t x32 = (size_t)NXS*512*XW*4;
  const size_t x16 = (size_t)NXS*512*XW*2;
  int plan; char* xring;
  if (used + x32 <= ws_size) { plan = 0; xring = alloc(x32); }
  else                       { plan = 1; xring = alloc(x16); }
  if (used > ws_size) return;

  const long SZG = (long)BB*2048;
  const long SZR = (long)BB*64;

  auto slotg = [&](int s, int l){ return accg + (long)((s&3)*3+l)*SZG; };
  auto slotr = [&](int s, int l){ return accr + (long)((s&3)*3+l)*SZR; };
  auto slotu = [&](int s, int j){ return ubuf + (long)((s&3)*2+j)*SZR; };
  auto slotw1= [&](int s){ return whb1 + (long)(s&1)*SZG; };
  auto slotw2= [&](int s){ return whb2 + (long)(s&1)*SZG; };
  auto hb    = [&](int s){ return HallR + (long)(s % NHS)*1536; };
  auto xrow  = [&](int s){ return (long)((((s>>2)&1)*NCH + (s&3))*512); };

  // ---- setup
  {
    long tot = (long)TT*BB*CC;
    k_xconv<<<dim3((tot + 255)/256), 256, 0, stream>>>(inputs, xb);
  }
  hipMemsetAsync(BXT,  0, (size_t)6400*512*2, stream);
  hipMemsetAsync(BG0T, 0, (size_t)6400*512*2, stream);
  hipMemsetAsync(BG1T, 0, (size_t)4352*512*2, stream);

  auto tp = [&](const float* src, long row_off, long srow, bf16* dstbase, long colbase, int N, int K){
    long total = (long)N*K;
    k_tpose<<<dim3((total + 255)/256), 256, 0, stream>>>(src + row_off*srow, srow, dstbase + colbase*K, K, total);
  };
  // BXT cols: [Wx0|Wr0|Wx1|Wr1|Wx2|Wr2|pad]
  tp(wx_w[0],0,2048, BXT,0,2048,512);   tp(wr_w[0],0,64, BXT,2048,64,512);
  tp(wx_w[1],0,2048, BXT,2112,2048,512);tp(wr_w[1],0,64, BXT,4160,64,512);
  tp(wx_w[2],0,2048, BXT,4224,2048,512);tp(wr_w[2],0,64, BXT,6272,64,512);
  // BG0T cols: [Wx1.h0|Wr1.h0|Wx2.h0|Wr2.h0|Wh0|Wl0|pad]
  tp(wx_w[1],512,2048, BG0T,0,2048,512);   tp(wr_w[1],512,64, BG0T,2048,64,512);
  tp(wx_w[2],512,2048, BG0T,2112,2048,512);tp(wr_w[2],512,64, BG0T,4160,64,512);
  tp(wh_w[0],0,2048,   BG0T,4224,2048,512);tp(wl_w[0],0,64,   BG0T,6272,64,512);
  // BG1T cols: [Wx2.h1|Wr2.h1|Wh1|Wl1|pad]
  tp(wx_w[2],1024,2048, BG1T,0,2048,512);  tp(wr_w[2],1024,64, BG1T,2048,64,512);
  tp(wh_w[1],0,2048,    BG1T,2112,2048,512);tp(wl_w[1],0,64,   BG1T,4160,64,512);
  tp(wh_w[2],0,2048, BG2T,0,2048,512);
  tp(proj_w,0,512, projT,0,512,1536);

  k_bias<<<dim3(24),256,0,stream>>>(wx_b[0],wh_b[0],wx_b[1],wh_b[1],wx_b[2],wh_b[2], biasg);
  hipMemsetAsync(ubuf, 0, (size_t)4*2*BB*64*4, stream);
  hipMemsetAsync(whb1, 0, (size_t)2*SZG*4, stream);
  hipMemsetAsync(whb2, 0, (size_t)2*SZG*4, stream);
  hipMemsetAsync(cbuf, 0, (size_t)3*BB*DD*4, stream);
  hipMemsetAsync(accg, 0, (size_t)SZG*4, stream);   // slotg(0,0): E0(0)'s h-part (h(-1)=0)
  k_dinit<<<dim3((3*BB*KK + 255)/256),256,0,stream>>>(init_keys, dbuf);

  // ---- pipelined recurrence.
  // A(t) = {E0(t),E1(t-1),E2(t-2)}
  // B(t) = {xchunk(t+2..t+5) if (t+2)%4==0, G0(t), G1(t-1), G2(t-2), proj(t-2)}
  for (int t = -2; t <= TT + 1; ++t) {
    // ----- A phase
    CArgs ca{}; ca.n = 0;
    auto addE = [&](int s, int l){
      CellDesc& e = ca.e[ca.n++];
      long ro = xrow(s)*XW + (long)l*2112;
      if (plan == 0) {
        e.xg = (void*)((float*)xring + ro);
        e.xr = (void*)((float*)xring + ro + 2048);
        e.xbf = 0;
      } else {
        e.xg = (void*)((bf16*)xring + ro);
        e.xr = (void*)((bf16*)xring + ro + 2048);
        e.xbf = 1;
      }
      e.gr = (l >= 1) ? slotr(s,l) : nullptr;
      e.gate = slotg(s,l);
      e.gate2 = (l==1) ? slotw1(s) : (l==2) ? slotw2(s) : nullptr;
      e.gate3 = (l==2) ? (g2b + (long)(s&1)*SZG) : nullptr;
      e.u0 = (l>=1) ? slotu(s-1,0) : nullptr;
      e.u1 = (l>=2) ? slotu(s-1,1) : nullptr;
      e.c = cbuf + (long)l*BB*DD; e.d = dbuf + (long)l*BB*KK;
      e.hout = hb(s) + (long)l*512;
    };
    if (t   >= 0 && t   < TT) addE(t,   0);
    if (t-1 >= 0 && t-1 < TT) addE(t-1, 1);
    if (t-2 >= 0 && t-2 < TT) addE(t-2, 2);
    if (ca.n)
      cell_batched<<<dim3(256, ca.n), 256, 0, stream>>>(ca, wd_w);

    // ----- B phase
    GArgs ga{}; ga.ng = 0;
    int cursor = 0;
    auto addG = [&](const bf16* A, long lda, const bf16* Bm, long ldb,
                    int mtiles, int ntiles, int order, int Kd, SegList sl){
      GDesc& g = ga.g[ga.ng++];
      g.A = A; g.lda = lda; g.B = Bm; g.ldb = ldb;
      g.mtiles = mtiles; g.ntiles = ntiles; g.tile_beg = cursor; g.order = order; g.K = Kd;
      cursor += mtiles * ntiles;
      g.segs = sl;
    };
    if (t+2 >= 0 && t+2 < TT && ((t+2) & (NCH-1)) == 0) {  // x-chunk for steps [t+2, t+2+NCH)
      int t0 = t+2;
      int steps = (TT - t0 < NCH) ? (TT - t0) : NCH;
      SegList sl{}; sl.n = 6;
      if (plan == 0) {
        float* x0 = (float*)xring + (long)(((t0>>2)&1)*NCH*512)*XW;
        sl.s[0] = { x0,      XW,    0, 0, biasg + 0    };
        sl.s[1] = { x0+2048, XW, 2048, 0, nullptr      };
        sl.s[2] = { x0+2112, XW, 2112, 0, biasg + 2048 };
        sl.s[3] = { x0+4160, XW, 4160, 0, nullptr      };
        sl.s[4] = { x0+4224, XW, 4224, 0, biasg + 4096 };
        sl.s[5] = { x0+6272, XW, 6272, 0, nullptr      };
      } else {
        bf16* x0 = (bf16*)xring + (long)(((t0>>2)&1)*NCH*512)*XW;
        sl.s[0] = { x0,      XW,    0, 2, biasg + 0    };
        sl.s[1] = { x0+2048, XW, 2048, 2, nullptr      };
        sl.s[2] = { x0+2112, XW, 2112, 2, biasg + 2048 };
        sl.s[3] = { x0+4160, XW, 4160, 2, nullptr      };
        sl.s[4] = { x0+4224, XW, 4224, 2, biasg + 4096 };
        sl.s[5] = { x0+6272, XW, 6272, 2, nullptr      };
      }
      // order=1 (mt-fast): each XCD covers a few nt columns -> B streams once
      // total (6.5 MB) instead of once per XCD; A (2 MB) is the L2-hot operand.
      addG(xb + (long)t0*512*512, 512, BXT, 512, steps*8, 50, 1, 512, sl);
    }
    if (t >= 0 && t < TT) {      // G0(t): h0-driven
      int s = t;
      SegList sl{}; sl.n = 7;
      sl.s[0] = { slotg(s,1),   2048,    0, 0, nullptr };
      sl.s[1] = { slotr(s,1),     64, 2048, 0, nullptr };
      sl.s[2] = { slotg(s,2),   2048, 2112, 0, nullptr };
      sl.s[3] = { slotr(s,2),     64, 4160, 0, nullptr };
      sl.s[4] = { slotg(s+1,0), 2048, 4224, 0, nullptr };  // Wh0 -> gate0(t+1)
      sl.s[5] = { slotu(s,0),     64, 6272, 0, nullptr };  // u0 = h0@Wl0
      sl.s[6] = { dump,          128, 6336, 0, nullptr };
      addG(hb(s), LDH, BG0T, 512, 8, 50, 1, 512, sl);
    }
    if (t-1 >= 0 && t-1 < TT) {  // G1(t-1): h1-driven
      int s = t-1;
      SegList sl{}; sl.n = 5;
      sl.s[0] = { g2b + (long)(s&1)*SZG, 2048, 0, 0, nullptr };  // Wx2[h1] -> gate3 ring (no RMW)
      sl.s[1] = { slotr(s,2),     64, 2048, 1, nullptr };        // Wr2[h1] += (tiny)
      sl.s[2] = { slotw1(s+1),  2048, 2112, 0, nullptr };        // Wh1*h1(s) -> whb1 ring
      sl.s[3] = { slotu(s,1),     64, 4160, 0, nullptr };        // u1 = h1@Wl1
      sl.s[4] = { dump,          128, 4224, 0, nullptr };
      addG(hb(s) + 512, LDH, BG1T, 512, 8, 34, 1, 512, sl);
    }
    if (t-2 >= 0 && t-2 <= TT-2) {  // G2(t-2): h2-driven
      int s = t-2;
      SegList sl{}; sl.n = 1;
      sl.s[0] = { slotw2(s+1), 2048, 0, 0, nullptr };      // Wh2*h2(s) -> whb2 ring
      addG(hb(s) + 1024, LDH, BG2T, 512, 8, 16, 1, 512, sl);
    }
    if (t-2 >= 0 && t-2 < TT) {  // proj(t-2): all three h layers of step s are final
      int s = t-2;
      SegList sl{}; sl.n = 1;
      sl.s[0] = { out + (long)s*512, (long)TT*512, 0, 0, proj_b };
      addG(hb(s), LDH, projT, 1536, 8, 4, 0, 1536, sl);
    }
    if (cursor) {
      ga.total = cursor; ga.chunk = (cursor + 7) / 8;
      gemm_batched<<<dim3(ga.chunk * 8), 256, 0, stream>>>(ga);
    }
  }
}

// Round 4
// 3277.372 us; speedup vs baseline: 1.1171x; 1.1171x over previous
//
#include <hip/hip_runtime.h>
#include <hip/hip_bf16.h>

typedef __hip_bfloat16 bf16;
typedef __attribute__((ext_vector_type(8))) short s16x8;
typedef __attribute__((ext_vector_type(4))) float f32x4;

// Problem constants
#define TT 55
#define BB 512
#define CC 512
#define DD 512
#define KK 64
#define NXS 8                    // x-ring slots (one step each)
#define NHS 8                    // Hall ring slots
#define LDH ((long)NHS*1536)     // Hall ring row stride
#define XW 6400L                 // XGR row width

typedef const __attribute__((address_space(1))) unsigned int gu32;
typedef __attribute__((address_space(3))) unsigned int lu32;
__device__ __forceinline__ void gload16(const void* g, void* l) {
  __builtin_amdgcn_global_load_lds((gu32*)g, (lu32*)l, 16, 0, 0);
}

struct Seg {
  void*  dst;          // destination base (float* or bf16* per mode)
  long   ldd;          // row stride (elements)
  int    col_begin;    // inclusive (GEMM N space), 64-aligned, sorted asc
  int    mode;         // 0 = f32 store (+bias), 1 = f32 +=, 2 = bf16 store (+bias)
  const float* bias;   // indexed by (col - col_begin), may be null
};
struct SegList { Seg s[8]; int n; };

struct GDesc {
  const bf16* A; const bf16* B;
  long lda, ldb;
  int mtiles, ntiles, tile_beg, order, K;  // order: 0=nt-fast, 1=mt-fast
  SegList segs;
};
struct GArgs { GDesc g[6]; int ng; int total; int chunk; };

// ---------------- batched GEMM: C[seg] (+)= A[MxK] * B^T[NxK], bf16 in, fp32 acc
// 64x128 tile (MxN), BK=64, 4 waves (2x2 of 32x64).
// Depth-1 double-buffered K-loop (2 LDS sets = 48 KB, preserves 3 blocks/CU):
// issue K-step k+1's global_load_lds BEFORE waiting on k (counted vmcnt(6)), so
// HBM/L2 latency hides under the previous step's 64 MFMAs. LDS XOR-swizzled
// (block p of row r holds global block p^(r&7)) - zero bank conflicts.
__global__ __launch_bounds__(256) void gemm_batched(GArgs args)
{
  __shared__ __align__(16) bf16 As[2][64][64];    // 2 x 8 KB
  __shared__ __align__(16) bf16 Bs[2][128][64];   // 2 x 16 KB

  // XCD-aware: bid%8 ~ XCD; each XCD gets a contiguous tile chunk.
  int tile = (int)(blockIdx.x & 7) * args.chunk + (int)(blockIdx.x >> 3);
  if (tile >= args.total) return;

  int gi = 0;
  for (int i = 1; i < args.ng; ++i) if (tile >= args.g[i].tile_beg) gi = i;
  const GDesc& g = args.g[gi];
  const int local = tile - g.tile_beg;
  int mt, nt;
  if (g.order == 1) { mt = local % g.mtiles; nt = local / g.mtiles; }
  else              { nt = local % g.ntiles; mt = local / g.ntiles; }

  const int tid  = threadIdx.x;
  const int wave = tid >> 6, lane = tid & 63;
  const int q = lane >> 4, mm = lane & 15;
  const int s7 = mm & 7;
  const int wm = wave >> 1, wn = wave & 1;
  const long m0 = (long)mt * 64;
  const long n0 = (long)nt * 128;

  const bf16* Ab = g.A + m0 * g.lda;
  const bf16* Bb = g.B + n0 * g.ldb;
  const long lda = g.lda, ldb = g.ldb;
  const int l8 = lane >> 3;                 // row within 8-row staging group
  const int gc = ((lane & 7) ^ l8) << 3;    // swizzled global col (elements)

  const int nk = g.K >> 6;                  // K-steps

  auto stage = [&](int b, int k0) {
#pragma unroll
    for (int p = 0; p < 2; ++p) {
      int r = p*32 + wave*8;
      gload16(Ab + (long)(r + l8)*lda + k0 + gc, &As[b][r][0]);
    }
#pragma unroll
    for (int p = 0; p < 4; ++p) {
      int r = p*32 + wave*8;
      gload16(Bb + (long)(r + l8)*ldb + k0 + gc, &Bs[b][r][0]);
    }
  };

  f32x4 acc[2][4] = {};

  stage(0, 0);                              // 6 loads in flight
  for (int k = 0; k < nk; ++k) {
    const int cur = k & 1;
    if (k + 1 < nk) {
      stage(cur ^ 1, (k + 1) << 6);         // 12 in flight
      asm volatile("s_waitcnt vmcnt(6)" ::: "memory");   // k's 6 landed
    } else {
      asm volatile("s_waitcnt vmcnt(0)" ::: "memory");
    }
    __builtin_amdgcn_s_barrier();           // all waves' k-data in LDS
#pragma unroll
    for (int kk = 0; kk < 64; kk += 32) {
      const int pc = ((((kk >> 3) + q) ^ s7) << 3);  // physical col of logical kk+q*8
      s16x8 av[2], bv[4];
#pragma unroll
      for (int i = 0; i < 2; ++i) av[i] = *(const s16x8*)&As[cur][wm*32 + i*16 + mm][pc];
#pragma unroll
      for (int j = 0; j < 4; ++j) bv[j] = *(const s16x8*)&Bs[cur][wn*64 + j*16 + mm][pc];
#pragma unroll
      for (int i = 0; i < 2; ++i)
#pragma unroll
        for (int j = 0; j < 4; ++j)
          acc[i][j] = __builtin_amdgcn_mfma_f32_16x16x32_bf16(av[i], bv[j], acc[i][j], 0,0,0);
    }
    __builtin_amdgcn_s_barrier();           // buf cur free for restage at k+2
  }

  // epilogue: segment lookup per 16-col group (boundaries are 64-aligned)
#pragma unroll
  for (int j = 0; j < 4; ++j) {
    int colbase = (int)n0 + wn*64 + j*16;
    Seg sg = g.segs.s[0];
    for (int i = 1; i < g.segs.n; ++i)
      if (colbase >= g.segs.s[i].col_begin) sg = g.segs.s[i];
    int dcol = colbase + mm - sg.col_begin;
    float bv = sg.bias ? sg.bias[dcol] : 0.0f;
#pragma unroll
    for (int i = 0; i < 2; ++i) {
      f32x4 a = acc[i][j];
#pragma unroll
      for (int r = 0; r < 4; ++r) {
        long row = m0 + wm*32 + i*16 + q*4 + r;  // C/D: col=lane&15, row=q*4+reg
        long off = row * sg.ldd + dcol;
        if (sg.mode == 1)      ((float*)sg.dst)[off] += a[r];
        else if (sg.mode == 2) ((bf16*)sg.dst)[off] = __float2bfloat16(a[r] + bv);
        else                   ((float*)sg.dst)[off] = a[r] + bv;
      }
    }
  }
}

// ---------------- batched cell update: up to 3 independent (step,layer) cells
struct CellDesc {
  const void* xg;      // x-driven gate part (row stride XW), fp32 or bf16 per xbf
  const void* xr;      // x-driven gr part (row stride XW)
  int xbf;             // 1 = xg/xr are bf16, 0 = fp32
  const float* gate;   // fp32 ring [512][2048]
  const float* gate2;  // extra addend (whb ring), may be null
  const float* gate3;  // extra addend (g2b ring), may be null
  const float* gr;     // fp32 [512][64], may be null
  const float* u0;     // may be null
  const float* u1;     // may be null
  float* c;            // [512][512]
  float* d;            // [512][64]
  bf16*  hout;         // row stride LDH
};
struct CArgs { CellDesc e[3]; int n; };

__device__ inline float sigm(float x){ return 1.0f/(1.0f + __expf(-x)); }
__device__ inline float ftanh(float x){ float e = __expf(2.0f*x); return 1.0f - 2.0f/(e + 1.0f); }

// 2 batch rows per block, grid (256, n).
__global__ __launch_bounds__(256) void cell_batched(CArgs a, const float* __restrict__ wd)
{
  const CellDesc e = a.e[blockIdx.y];
  const int tid = threadIdx.x;
  const int r0 = blockIdx.x * 2;
  __shared__ float dn[2][64];

  if (tid < 128) {
    int r = tid >> 6, k = tid & 63;
    long row = r0 + r;
    float gv = e.xbf ? __bfloat162float(((const bf16*)e.xr)[row*XW + k])
                     : ((const float*)e.xr)[row*XW + k];
    if (e.gr) gv += e.gr[row*64 + k];
    if (e.u0) gv += (1.0f/3.0f)*e.u0[row*64 + k];
    if (e.u1) gv += (1.0f/3.0f)*e.u1[row*64 + k];
    float rr = sigm(gv);
    float dv = rr * e.d[row*64 + k];
    e.d[row*64 + k] = dv;
    dn[r][k] = dv;
  }
  __syncthreads();

  float accv[2][2] = {};
#pragma unroll 4
  for (int k = 0; k < 64; ++k) {
    float w0 = wd[k*512 + tid];
    float w1 = wd[k*512 + tid + 256];
#pragma unroll
    for (int r = 0; r < 2; ++r) {
      float dv = dn[r][k];
      accv[0][r] += dv * w0;
      accv[1][r] += dv * w1;
    }
  }

#pragma unroll
  for (int half = 0; half < 2; ++half) {
    int n = tid + half*256;
#pragma unroll
    for (int r = 0; r < 2; ++r) {
      long row = r0 + r;
      const float* gg = e.gate + row*2048;
      float fv = gg[n], iv = gg[512+n], ov = gg[1024+n], cb = gg[1536+n];
      if (e.gate2) {
        const float* g2 = e.gate2 + row*2048;
        fv += g2[n]; iv += g2[512+n]; ov += g2[1024+n]; cb += g2[1536+n];
      }
      if (e.gate3) {
        const float* g3 = e.gate3 + row*2048;
        fv += g3[n]; iv += g3[512+n]; ov += g3[1024+n]; cb += g3[1536+n];
      }
      if (e.xbf) {
        const bf16* xg = (const bf16*)e.xg + row*XW;
        fv += __bfloat162float(xg[n]);      iv += __bfloat162float(xg[512+n]);
        ov += __bfloat162float(xg[1024+n]); cb += __bfloat162float(xg[1536+n]);
      } else {
        const float* xg = (const float*)e.xg + row*XW;
        fv += xg[n]; iv += xg[512+n]; ov += xg[1024+n]; cb += xg[1536+n];
      }
      fv = sigm(fv); iv = sigm(iv); ov = sigm(ov); cb = ftanh(cb);
      float cv = fv * e.c[row*512 + n] + iv * cb + ftanh(accv[half][r]);
      e.c[row*512 + n] = cv;
      e.hout[row*LDH + n] = __float2bfloat16(ov * ftanh(cv));
    }
  }
}

// ---------------- setup kernels
__global__ void k_tpose(const float* __restrict__ src, long srow,
                        bf16* __restrict__ dst, int K, long total)
{
  long idx = (long)blockIdx.x * 256 + threadIdx.x;
  if (idx >= total) return;
  long n = idx / K;
  long k = idx - n * K;
  dst[idx] = __float2bfloat16(src[k * srow + n]);
}

__global__ void k_xconv(const float* __restrict__ x, bf16* __restrict__ xb)
{
  long i = (long)blockIdx.x * 256 + threadIdx.x;
  if (i >= (long)TT*BB*CC) return;
  int cc = (int)(i & 511);
  long r = i >> 9;
  int t = (int)(r / BB), b = (int)(r - (long)t*BB);
  xb[i] = __float2bfloat16(x[((long)b*TT + t)*CC + cc]);
}

__global__ void k_bias(const float* b0,const float* b1,const float* b2,
                       const float* b3,const float* b4,const float* b5,
                       float* out)
{
  int i = blockIdx.x*256 + threadIdx.x;
  if (i < 2048)      out[i] = b0[i] + b1[i];
  else if (i < 4096) out[i] = b2[i-2048] + b3[i-2048];
  else if (i < 6144) out[i] = b4[i-4096] + b5[i-4096];
}

__global__ void k_dinit(const float* __restrict__ keys, float* __restrict__ d)
{
  int i = blockIdx.x*256 + threadIdx.x;
  if (i < 3*BB*KK) d[i] = keys[i % (BB*KK)];
}

// ---------------- host
extern "C" void kernel_launch(void* const* d_in, const int* in_sizes, int n_in,
                              void* d_out, int out_size, void* d_ws, size_t ws_size,
                              hipStream_t stream)
{
  const float* inputs    = (const float*)d_in[0];
  const float* init_keys = (const float*)d_in[1];
  const float* wx_w[3] = {(const float*)d_in[2],  (const float*)d_in[8],  (const float*)d_in[14]};
  const float* wx_b[3] = {(const float*)d_in[3],  (const float*)d_in[9],  (const float*)d_in[15]};
  const float* wh_w[3] = {(const float*)d_in[4],  (const float*)d_in[10], (const float*)d_in[16]};
  const float* wh_b[3] = {(const float*)d_in[5],  (const float*)d_in[11], (const float*)d_in[17]};
  const float* wr_w[3] = {(const float*)d_in[6],  (const float*)d_in[12], (const float*)d_in[18]};
  const float* wl_w[3] = {(const float*)d_in[7],  (const float*)d_in[13], (const float*)d_in[19]};
  const float* wd_w   = (const float*)d_in[20];
  const float* proj_w = (const float*)d_in[21];
  const float* proj_b = (const float*)d_in[22];
  float* out = (float*)d_out;

  char* wsp = (char*)d_ws;
  size_t used = 0;
  auto alloc = [&](size_t bytes) {
    char* p = wsp + used;
    used += (bytes + 255) & ~(size_t)255;
    return p;
  };
  bf16* xb    = (bf16*)alloc((size_t)TT*BB*CC*2);        // [t][b][c] = [28160][512]
  bf16* BXT   = (bf16*)alloc((size_t)6400*512*2);        // x-driven  B^T (padded)
  bf16* BG0T  = (bf16*)alloc((size_t)6400*512*2);        // h0-driven B^T (padded)
  bf16* BG1T  = (bf16*)alloc((size_t)4352*512*2);        // h1-driven B^T (padded)
  bf16* BG2T  = (bf16*)alloc((size_t)2048*512*2);        // h2-driven B^T
  bf16* projT = (bf16*)alloc((size_t)512*1536*2);
  bf16* HallR = (bf16*)alloc((size_t)BB*NHS*1536*2);     // h ring [b][slot][3*512]
  float* accg = (float*)alloc((size_t)4*3*BB*2048*4);    // [slot][l][b][2048]
  float* accr = (float*)alloc((size_t)4*3*BB*64*4);      // [slot][l][b][64]
  float* ubuf = (float*)alloc((size_t)4*2*BB*64*4);      // [slot][j][b][64]
  float* whb1 = (float*)alloc((size_t)2*BB*2048*4);      // Wh1*h1 ring
  float* whb2 = (float*)alloc((size_t)2*BB*2048*4);      // Wh2*h2 ring
  float* g2b  = (float*)alloc((size_t)2*BB*2048*4);      // Wx2[h1-part]*h1 ring (no RMW)
  float* cbuf = (float*)alloc((size_t)3*BB*DD*4);
  float* dbuf = (float*)alloc((size_t)3*BB*KK*4);
  float* biasg= (float*)alloc((size_t)3*2048*4);
  float* dump = (float*)alloc((size_t)BB*128*4);         // pad-column sink

  // x-ring: NXS one-step slots; fp32 if it fits, else bf16
  const size_t x32 = (size_t)NXS*512*XW*4;
  const size_t x16 = (size_t)NXS*512*XW*2;
  int plan; char* xring;
  if (used + x32 <= ws_size) { plan = 0; xring = alloc(x32); }
  else                       { plan = 1; xring = alloc(x16); }
  if (used > ws_size) return;

  const long SZG = (long)BB*2048;
  const long SZR = (long)BB*64;

  auto slotg = [&](int s, int l){ return accg + (long)((s&3)*3+l)*SZG; };
  auto slotr = [&](int s, int l){ return accr + (long)((s&3)*3+l)*SZR; };
  auto slotu = [&](int s, int j){ return ubuf + (long)((s&3)*2+j)*SZR; };
  auto slotw1= [&](int s){ return whb1 + (long)(s&1)*SZG; };
  auto slotw2= [&](int s){ return whb2 + (long)(s&1)*SZG; };
  auto hb    = [&](int s){ return HallR + (long)(s % NHS)*1536; };
  auto xrow  = [&](int s){ return (long)((s & (NXS-1))*512); };

  // ---- setup
  {
    long tot = (long)TT*BB*CC;
    k_xconv<<<dim3((tot + 255)/256), 256, 0, stream>>>(inputs, xb);
  }
  hipMemsetAsync(BXT,  0, (size_t)6400*512*2, stream);
  hipMemsetAsync(BG0T, 0, (size_t)6400*512*2, stream);
  hipMemsetAsync(BG1T, 0, (size_t)4352*512*2, stream);

  auto tp = [&](const float* src, long row_off, long srow, bf16* dstbase, long colbase, int N, int K){
    long total = (long)N*K;
    k_tpose<<<dim3((total + 255)/256), 256, 0, stream>>>(src + row_off*srow, srow, dstbase + colbase*K, K, total);
  };
  // BXT cols: [Wx0|Wr0|Wx1|Wr1|Wx2|Wr2|pad]
  tp(wx_w[0],0,2048, BXT,0,2048,512);   tp(wr_w[0],0,64, BXT,2048,64,512);
  tp(wx_w[1],0,2048, BXT,2112,2048,512);tp(wr_w[1],0,64, BXT,4160,64,512);
  tp(wx_w[2],0,2048, BXT,4224,2048,512);tp(wr_w[2],0,64, BXT,6272,64,512);
  // BG0T cols: [Wx1.h0|Wr1.h0|Wx2.h0|Wr2.h0|Wh0|Wl0|pad]
  tp(wx_w[1],512,2048, BG0T,0,2048,512);   tp(wr_w[1],512,64, BG0T,2048,64,512);
  tp(wx_w[2],512,2048, BG0T,2112,2048,512);tp(wr_w[2],512,64, BG0T,4160,64,512);
  tp(wh_w[0],0,2048,   BG0T,4224,2048,512);tp(wl_w[0],0,64,   BG0T,6272,64,512);
  // BG1T cols: [Wx2.h1|Wr2.h1|Wh1|Wl1|pad]
  tp(wx_w[2],1024,2048, BG1T,0,2048,512);  tp(wr_w[2],1024,64, BG1T,2048,64,512);
  tp(wh_w[1],0,2048,    BG1T,2112,2048,512);tp(wl_w[1],0,64,   BG1T,4160,64,512);
  tp(wh_w[2],0,2048, BG2T,0,2048,512);
  tp(proj_w,0,512, projT,0,512,1536);

  k_bias<<<dim3(24),256,0,stream>>>(wx_b[0],wh_b[0],wx_b[1],wh_b[1],wx_b[2],wh_b[2], biasg);
  hipMemsetAsync(ubuf, 0, (size_t)4*2*BB*64*4, stream);
  hipMemsetAsync(whb1, 0, (size_t)2*SZG*4, stream);
  hipMemsetAsync(whb2, 0, (size_t)2*SZG*4, stream);
  hipMemsetAsync(cbuf, 0, (size_t)3*BB*DD*4, stream);
  hipMemsetAsync(accg, 0, (size_t)SZG*4, stream);   // slotg(0,0): E0(0)'s h-part (h(-1)=0)
  k_dinit<<<dim3((3*BB*KK + 255)/256),256,0,stream>>>(init_keys, dbuf);

  // ---- pipelined recurrence.
  // A(t) = {E0(t),E1(t-1),E2(t-2)}
  // B(t) = {X(t+5), G0(t), G1(t-1), G2(t-2), proj(t-2)} - X has no dep on A(t),
  // it fills CUs while the dependent groups' K-chains drain. Prologue: B(-2)
  // computes x-steps 0..2, B(-1) steps 3..4; x(s) written at B(s-5), slot s%8,
  // last read at A(s+2) -> slot reuse (s vs s-8) is race-free.
  for (int t = -2; t <= TT + 1; ++t) {
    // ----- A phase
    CArgs ca{}; ca.n = 0;
    auto addE = [&](int s, int l){
      CellDesc& e = ca.e[ca.n++];
      long ro = xrow(s)*XW + (long)l*2112;
      if (plan == 0) {
        e.xg = (void*)((float*)xring + ro);
        e.xr = (void*)((float*)xring + ro + 2048);
        e.xbf = 0;
      } else {
        e.xg = (void*)((bf16*)xring + ro);
        e.xr = (void*)((bf16*)xring + ro + 2048);
        e.xbf = 1;
      }
      e.gr = (l >= 1) ? slotr(s,l) : nullptr;
      e.gate = slotg(s,l);
      e.gate2 = (l==1) ? slotw1(s) : (l==2) ? slotw2(s) : nullptr;
      e.gate3 = (l==2) ? (g2b + (long)(s&1)*SZG) : nullptr;
      e.u0 = (l>=1) ? slotu(s-1,0) : nullptr;
      e.u1 = (l>=2) ? slotu(s-1,1) : nullptr;
      e.c = cbuf + (long)l*BB*DD; e.d = dbuf + (long)l*BB*KK;
      e.hout = hb(s) + (long)l*512;
    };
    if (t   >= 0 && t   < TT) addE(t,   0);
    if (t-1 >= 0 && t-1 < TT) addE(t-1, 1);
    if (t-2 >= 0 && t-2 < TT) addE(t-2, 2);
    if (ca.n)
      cell_batched<<<dim3(256, ca.n), 256, 0, stream>>>(ca, wd_w);

    // ----- B phase
    GArgs ga{}; ga.ng = 0;
    int cursor = 0;
    auto addG = [&](const bf16* A, long lda, const bf16* Bm, long ldb,
                    int mtiles, int ntiles, int order, int Kd, SegList sl){
      GDesc& g = ga.g[ga.ng++];
      g.A = A; g.lda = lda; g.B = Bm; g.ldb = ldb;
      g.mtiles = mtiles; g.ntiles = ntiles; g.tile_beg = cursor; g.order = order; g.K = Kd;
      cursor += mtiles * ntiles;
      g.segs = sl;
    };
    auto addX = [&](int s0, int nsteps){   // x-GEMM for steps [s0, s0+nsteps)
      SegList sl{}; sl.n = 6;
      if (plan == 0) {
        float* x0 = (float*)xring + xrow(s0)*XW;
        sl.s[0] = { x0,      XW,    0, 0, biasg + 0    };
        sl.s[1] = { x0+2048, XW, 2048, 0, nullptr      };
        sl.s[2] = { x0+2112, XW, 2112, 0, biasg + 2048 };
        sl.s[3] = { x0+4160, XW, 4160, 0, nullptr      };
        sl.s[4] = { x0+4224, XW, 4224, 0, biasg + 4096 };
        sl.s[5] = { x0+6272, XW, 6272, 0, nullptr      };
      } else {
        bf16* x0 = (bf16*)xring + xrow(s0)*XW;
        sl.s[0] = { x0,      XW,    0, 2, biasg + 0    };
        sl.s[1] = { x0+2048, XW, 2048, 2, nullptr      };
        sl.s[2] = { x0+2112, XW, 2112, 2, biasg + 2048 };
        sl.s[3] = { x0+4160, XW, 4160, 2, nullptr      };
        sl.s[4] = { x0+4224, XW, 4224, 2, biasg + 4096 };
        sl.s[5] = { x0+6272, XW, 6272, 2, nullptr      };
      }
      addG(xb + (long)s0*512*512, 512, BXT, 512, nsteps*8, 50, 1, 512, sl);
    };
    if (t == -2)                     addX(0, 3);
    else if (t == -1)                addX(3, 2);
    else if (t >= 0 && t + 5 < TT)   addX(t + 5, 1);
    if (t >= 0 && t < TT) {      // G0(t): h0-driven
      int s = t;
      SegList sl{}; sl.n = 7;
      sl.s[0] = { slotg(s,1),   2048,    0, 0, nullptr };
      sl.s[1] = { slotr(s,1),     64, 2048, 0, nullptr };
      sl.s[2] = { slotg(s,2),   2048, 2112, 0, nullptr };
      sl.s[3] = { slotr(s,2),     64, 4160, 0, nullptr };
      sl.s[4] = { slotg(s+1,0), 2048, 4224, 0, nullptr };  // Wh0 -> gate0(t+1)
      sl.s[5] = { slotu(s,0),     64, 6272, 0, nullptr };  // u0 = h0@Wl0
      sl.s[6] = { dump,          128, 6336, 0, nullptr };
      addG(hb(s), LDH, BG0T, 512, 8, 50, 1, 512, sl);
    }
    if (t-1 >= 0 && t-1 < TT) {  // G1(t-1): h1-driven
      int s = t-1;
      SegList sl{}; sl.n = 5;
      sl.s[0] = { g2b + (long)(s&1)*SZG, 2048, 0, 0, nullptr };  // Wx2[h1] -> gate3 ring (no RMW)
      sl.s[1] = { slotr(s,2),     64, 2048, 1, nullptr };        // Wr2[h1] += (tiny)
      sl.s[2] = { slotw1(s+1),  2048, 2112, 0, nullptr };        // Wh1*h1(s) -> whb1 ring
      sl.s[3] = { slotu(s,1),     64, 4160, 0, nullptr };        // u1 = h1@Wl1
      sl.s[4] = { dump,          128, 4224, 0, nullptr };
      addG(hb(s) + 512, LDH, BG1T, 512, 8, 34, 1, 512, sl);
    }
    if (t-2 >= 0 && t-2 <= TT-2) {  // G2(t-2): h2-driven
      int s = t-2;
      SegList sl{}; sl.n = 1;
      sl.s[0] = { slotw2(s+1), 2048, 0, 0, nullptr };      // Wh2*h2(s) -> whb2 ring
      addG(hb(s) + 1024, LDH, BG2T, 512, 8, 16, 1, 512, sl);
    }
    if (t-2 >= 0 && t-2 < TT) {  // proj(t-2): all three h layers of step s are final
      int s = t-2;
      SegList sl{}; sl.n = 1;
      sl.s[0] = { out + (long)s*512, (long)TT*512, 0, 0, proj_b };
      addG(hb(s), LDH, projT, 1536, 8, 4, 0, 1536, sl);
    }
    if (cursor) {
      ga.total = cursor; ga.chunk = (cursor + 7) / 8;
      gemm_batched<<<dim3(ga.chunk * 8), 256, 0, stream>>>(ga);
    }
  }
}

// Round 5
// 2997.098 us; speedup vs baseline: 1.2216x; 1.0935x over previous
//
#include <hip/hip_runtime.h>
#include <hip/hip_bf16.h>

typedef __hip_bfloat16 bf16;
typedef __attribute__((ext_vector_type(8))) short s16x8;
typedef __attribute__((ext_vector_type(4))) float f32x4;

// Problem constants
#define TT 55
#define BB 512
#define CC 512
#define DD 512
#define KK 64
#define NXS 8                    // x-ring slots (one step each)
#define NHS 8                    // Hall ring slots
#define LDH ((long)NHS*1536)     // Hall ring row stride
#define XW 6400L                 // XGR row width

typedef const __attribute__((address_space(1))) unsigned int gu32;
typedef __attribute__((address_space(3))) unsigned int lu32;
__device__ __forceinline__ void gload16(const void* g, void* l) {
  __builtin_amdgcn_global_load_lds((gu32*)g, (lu32*)l, 16, 0, 0);
}

struct Seg {
  void*  dst;          // destination base (float* or bf16* per mode)
  long   ldd;          // row stride (elements)
  int    col_begin;    // inclusive (GEMM N space), 64-aligned, sorted asc
  int    mode;         // 0 = f32 store (+bias), 1 = f32 +=, 2 = bf16 store (+bias)
  const float* bias;   // indexed by (col - col_begin), may be null
};
struct SegList { Seg s[8]; int n; };

struct GDesc {
  const bf16* A; const bf16* B;
  long lda, ldb;
  int mtiles, ntiles, tile_beg, order, K;  // order: 0=nt-fast, 1=mt-fast
  SegList segs;
};
struct GArgs { GDesc g[6]; int ng; int total; int chunk; };

// ---------------- batched GEMM: C[seg] (+)= A[MxK] * B^T[NxK], bf16 in, fp32 acc
// 64x128 tile (MxN), BK=64, 4 waves (2x2 of 32x64).
// Single-buffered 24 KB LDS -> 6 blocks/CU. On these small latency-bound phases
// cross-block TLP hides the per-step drain better than intra-block pipelining
// (measured r0 vs r2/r4: 24KB single-buf 24.5ns/tile; 48KB dbuf 33; 72KB 3-buf 50).
// LDS XOR-swizzled (block p of row r holds global block p^(r&7)) - no bank conflicts.
__global__ __launch_bounds__(256) void gemm_batched(GArgs args)
{
  __shared__ __align__(16) bf16 As[64][64];    // 8 KB
  __shared__ __align__(16) bf16 Bs[128][64];   // 16 KB

  // XCD-aware: bid%8 ~ XCD; each XCD gets a contiguous tile chunk.
  int tile = (int)(blockIdx.x & 7) * args.chunk + (int)(blockIdx.x >> 3);
  if (tile >= args.total) return;

  int gi = 0;
  for (int i = 1; i < args.ng; ++i) if (tile >= args.g[i].tile_beg) gi = i;
  const GDesc& g = args.g[gi];
  const int local = tile - g.tile_beg;
  int mt, nt;
  if (g.order == 1) { mt = local % g.mtiles; nt = local / g.mtiles; }
  else              { nt = local % g.ntiles; mt = local / g.ntiles; }

  const int tid  = threadIdx.x;
  const int wave = tid >> 6, lane = tid & 63;
  const int q = lane >> 4, mm = lane & 15;
  const int s7 = mm & 7;
  const int wm = wave >> 1, wn = wave & 1;
  const long m0 = (long)mt * 64;
  const long n0 = (long)nt * 128;

  const bf16* Ab = g.A + m0 * g.lda;
  const bf16* Bb = g.B + n0 * g.ldb;
  const long lda = g.lda, ldb = g.ldb;
  const int l8 = lane >> 3;                 // row within 8-row staging group
  const int gc = ((lane & 7) ^ l8) << 3;    // swizzled global col (elements)

  f32x4 acc[2][4] = {};

  for (int k0 = 0; k0 < g.K; k0 += 64) {
#pragma unroll
    for (int p = 0; p < 2; ++p) {
      int r = p*32 + wave*8;
      gload16(Ab + (long)(r + l8)*lda + k0 + gc, &As[r][0]);
    }
#pragma unroll
    for (int p = 0; p < 4; ++p) {
      int r = p*32 + wave*8;
      gload16(Bb + (long)(r + l8)*ldb + k0 + gc, &Bs[r][0]);
    }
    asm volatile("s_waitcnt vmcnt(0)" ::: "memory");
    __builtin_amdgcn_s_barrier();
#pragma unroll
    for (int kk = 0; kk < 64; kk += 32) {
      const int pc = ((((kk >> 3) + q) ^ s7) << 3);  // physical col of logical kk+q*8
      s16x8 av[2], bv[4];
#pragma unroll
      for (int i = 0; i < 2; ++i) av[i] = *(const s16x8*)&As[wm*32 + i*16 + mm][pc];
#pragma unroll
      for (int j = 0; j < 4; ++j) bv[j] = *(const s16x8*)&Bs[wn*64 + j*16 + mm][pc];
#pragma unroll
      for (int i = 0; i < 2; ++i)
#pragma unroll
        for (int j = 0; j < 4; ++j)
          acc[i][j] = __builtin_amdgcn_mfma_f32_16x16x32_bf16(av[i], bv[j], acc[i][j], 0,0,0);
    }
    __builtin_amdgcn_s_barrier();
  }

  // epilogue: segment lookup per 16-col group (boundaries are 64-aligned)
#pragma unroll
  for (int j = 0; j < 4; ++j) {
    int colbase = (int)n0 + wn*64 + j*16;
    Seg sg = g.segs.s[0];
    for (int i = 1; i < g.segs.n; ++i)
      if (colbase >= g.segs.s[i].col_begin) sg = g.segs.s[i];
    int dcol = colbase + mm - sg.col_begin;
    float bv = sg.bias ? sg.bias[dcol] : 0.0f;
#pragma unroll
    for (int i = 0; i < 2; ++i) {
      f32x4 a = acc[i][j];
#pragma unroll
      for (int r = 0; r < 4; ++r) {
        long row = m0 + wm*32 + i*16 + q*4 + r;  // C/D: col=lane&15, row=q*4+reg
        long off = row * sg.ldd + dcol;
        if (sg.mode == 1)      ((float*)sg.dst)[off] += a[r];
        else if (sg.mode == 2) ((bf16*)sg.dst)[off] = __float2bfloat16(a[r] + bv);
        else                   ((float*)sg.dst)[off] = a[r] + bv;
      }
    }
  }
}

// ---------------- batched cell update: up to 3 independent (step,layer) cells
struct CellDesc {
  const void* xg;      // x-driven gate part (row stride XW), fp32 or bf16 per xbf
  const void* xr;      // x-driven gr part (row stride XW)
  int xbf;             // 1 = xg/xr are bf16, 0 = fp32
  const float* gate;   // fp32 ring [512][2048]
  const float* gate2;  // extra addend (whb ring), may be null
  const float* gate3;  // extra addend (g2b ring), may be null
  const float* gr;     // fp32 [512][64], may be null
  const float* u0;     // may be null
  const float* u1;     // may be null
  float* c;            // [512][512]
  float* d;            // [512][64]
  bf16*  hout;         // row stride LDH
};
struct CArgs { CellDesc e[3]; int n; };

__device__ inline float sigm(float x){ return 1.0f/(1.0f + __expf(-x)); }
__device__ inline float ftanh(float x){ float e = __expf(2.0f*x); return 1.0f - 2.0f/(e + 1.0f); }

// 2 batch rows per block, grid (256, n).
__global__ __launch_bounds__(256) void cell_batched(CArgs a, const float* __restrict__ wd)
{
  const CellDesc e = a.e[blockIdx.y];
  const int tid = threadIdx.x;
  const int r0 = blockIdx.x * 2;
  __shared__ float dn[2][64];

  if (tid < 128) {
    int r = tid >> 6, k = tid & 63;
    long row = r0 + r;
    float gv = e.xbf ? __bfloat162float(((const bf16*)e.xr)[row*XW + k])
                     : ((const float*)e.xr)[row*XW + k];
    if (e.gr) gv += e.gr[row*64 + k];
    if (e.u0) gv += (1.0f/3.0f)*e.u0[row*64 + k];
    if (e.u1) gv += (1.0f/3.0f)*e.u1[row*64 + k];
    float rr = sigm(gv);
    float dv = rr * e.d[row*64 + k];
    e.d[row*64 + k] = dv;
    dn[r][k] = dv;
  }
  __syncthreads();

  float accv[2][2] = {};
#pragma unroll 4
  for (int k = 0; k < 64; ++k) {
    float w0 = wd[k*512 + tid];
    float w1 = wd[k*512 + tid + 256];
#pragma unroll
    for (int r = 0; r < 2; ++r) {
      float dv = dn[r][k];
      accv[0][r] += dv * w0;
      accv[1][r] += dv * w1;
    }
  }

#pragma unroll
  for (int half = 0; half < 2; ++half) {
    int n = tid + half*256;
#pragma unroll
    for (int r = 0; r < 2; ++r) {
      long row = r0 + r;
      const float* gg = e.gate + row*2048;
      float fv = gg[n], iv = gg[512+n], ov = gg[1024+n], cb = gg[1536+n];
      if (e.gate2) {
        const float* g2 = e.gate2 + row*2048;
        fv += g2[n]; iv += g2[512+n]; ov += g2[1024+n]; cb += g2[1536+n];
      }
      if (e.gate3) {
        const float* g3 = e.gate3 + row*2048;
        fv += g3[n]; iv += g3[512+n]; ov += g3[1024+n]; cb += g3[1536+n];
      }
      if (e.xbf) {
        const bf16* xg = (const bf16*)e.xg + row*XW;
        fv += __bfloat162float(xg[n]);      iv += __bfloat162float(xg[512+n]);
        ov += __bfloat162float(xg[1024+n]); cb += __bfloat162float(xg[1536+n]);
      } else {
        const float* xg = (const float*)e.xg + row*XW;
        fv += xg[n]; iv += xg[512+n]; ov += xg[1024+n]; cb += xg[1536+n];
      }
      fv = sigm(fv); iv = sigm(iv); ov = sigm(ov); cb = ftanh(cb);
      float cv = fv * e.c[row*512 + n] + iv * cb + ftanh(accv[half][r]);
      e.c[row*512 + n] = cv;
      e.hout[row*LDH + n] = __float2bfloat16(ov * ftanh(cv));
    }
  }
}

// ---------------- setup kernels
__global__ void k_tpose(const float* __restrict__ src, long srow,
                        bf16* __restrict__ dst, int K, long total)
{
  long idx = (long)blockIdx.x * 256 + threadIdx.x;
  if (idx >= total) return;
  long n = idx / K;
  long k = idx - n * K;
  dst[idx] = __float2bfloat16(src[k * srow + n]);
}

__global__ void k_xconv(const float* __restrict__ x, bf16* __restrict__ xb)
{
  long i = (long)blockIdx.x * 256 + threadIdx.x;
  if (i >= (long)TT*BB*CC) return;
  int cc = (int)(i & 511);
  long r = i >> 9;
  int t = (int)(r / BB), b = (int)(r - (long)t*BB);
  xb[i] = __float2bfloat16(x[((long)b*TT + t)*CC + cc]);
}

__global__ void k_bias(const float* b0,const float* b1,const float* b2,
                       const float* b3,const float* b4,const float* b5,
                       float* out)
{
  int i = blockIdx.x*256 + threadIdx.x;
  if (i < 2048)      out[i] = b0[i] + b1[i];
  else if (i < 4096) out[i] = b2[i-2048] + b3[i-2048];
  else if (i < 6144) out[i] = b4[i-4096] + b5[i-4096];
}

__global__ void k_dinit(const float* __restrict__ keys, float* __restrict__ d)
{
  int i = blockIdx.x*256 + threadIdx.x;
  if (i < 3*BB*KK) d[i] = keys[i % (BB*KK)];
}

// ---------------- host
extern "C" void kernel_launch(void* const* d_in, const int* in_sizes, int n_in,
                              void* d_out, int out_size, void* d_ws, size_t ws_size,
                              hipStream_t stream)
{
  const float* inputs    = (const float*)d_in[0];
  const float* init_keys = (const float*)d_in[1];
  const float* wx_w[3] = {(const float*)d_in[2],  (const float*)d_in[8],  (const float*)d_in[14]};
  const float* wx_b[3] = {(const float*)d_in[3],  (const float*)d_in[9],  (const float*)d_in[15]};
  const float* wh_w[3] = {(const float*)d_in[4],  (const float*)d_in[10], (const float*)d_in[16]};
  const float* wh_b[3] = {(const float*)d_in[5],  (const float*)d_in[11], (const float*)d_in[17]};
  const float* wr_w[3] = {(const float*)d_in[6],  (const float*)d_in[12], (const float*)d_in[18]};
  const float* wl_w[3] = {(const float*)d_in[7],  (const float*)d_in[13], (const float*)d_in[19]};
  const float* wd_w   = (const float*)d_in[20];
  const float* proj_w = (const float*)d_in[21];
  const float* proj_b = (const float*)d_in[22];
  float* out = (float*)d_out;

  char* wsp = (char*)d_ws;
  size_t used = 0;
  auto alloc = [&](size_t bytes) {
    char* p = wsp + used;
    used += (bytes + 255) & ~(size_t)255;
    return p;
  };
  bf16* xb    = (bf16*)alloc((size_t)TT*BB*CC*2);        // [t][b][c] = [28160][512]
  bf16* BXT   = (bf16*)alloc((size_t)6400*512*2);        // x-driven  B^T (padded)
  bf16* BG0T  = (bf16*)alloc((size_t)6400*512*2);        // h0-driven B^T (padded)
  bf16* BG1T  = (bf16*)alloc((size_t)4352*512*2);        // h1-driven B^T (padded)
  bf16* BG2T  = (bf16*)alloc((size_t)2048*512*2);        // h2-driven B^T
  bf16* projT = (bf16*)alloc((size_t)512*1536*2);
  bf16* HallR = (bf16*)alloc((size_t)BB*NHS*1536*2);     // h ring [b][slot][3*512]
  float* accg = (float*)alloc((size_t)4*3*BB*2048*4);    // [slot][l][b][2048]
  float* accr = (float*)alloc((size_t)4*3*BB*64*4);      // [slot][l][b][64]
  float* ubuf = (float*)alloc((size_t)4*2*BB*64*4);      // [slot][j][b][64]
  float* whb1 = (float*)alloc((size_t)2*BB*2048*4);      // Wh1*h1 ring
  float* whb2 = (float*)alloc((size_t)2*BB*2048*4);      // Wh2*h2 ring
  float* g2b  = (float*)alloc((size_t)2*BB*2048*4);      // Wx2[h1-part]*h1 ring (no RMW)
  float* cbuf = (float*)alloc((size_t)3*BB*DD*4);
  float* dbuf = (float*)alloc((size_t)3*BB*KK*4);
  float* biasg= (float*)alloc((size_t)3*2048*4);
  float* dump = (float*)alloc((size_t)BB*128*4);         // pad-column sink

  // x-ring: NXS one-step slots; fp32 if it fits, else bf16
  const size_t x32 = (size_t)NXS*512*XW*4;
  const size_t x16 = (size_t)NXS*512*XW*2;
  int plan; char* xring;
  if (used + x32 <= ws_size) { plan = 0; xring = alloc(x32); }
  else                       { plan = 1; xring = alloc(x16); }
  if (used > ws_size) return;

  const long SZG = (long)BB*2048;
  const long SZR = (long)BB*64;

  auto slotg = [&](int s, int l){ return accg + (long)((s&3)*3+l)*SZG; };
  auto slotr = [&](int s, int l){ return accr + (long)((s&3)*3+l)*SZR; };
  auto slotu = [&](int s, int j){ return ubuf + (long)((s&3)*2+j)*SZR; };
  auto slotw1= [&](int s){ return whb1 + (long)(s&1)*SZG; };
  auto slotw2= [&](int s){ return whb2 + (long)(s&1)*SZG; };
  auto hb    = [&](int s){ return HallR + (long)(s % NHS)*1536; };
  auto xrow  = [&](int s){ return (long)((s & (NXS-1))*512); };

  // ---- setup
  {
    long tot = (long)TT*BB*CC;
    k_xconv<<<dim3((tot + 255)/256), 256, 0, stream>>>(inputs, xb);
  }
  hipMemsetAsync(BXT,  0, (size_t)6400*512*2, stream);
  hipMemsetAsync(BG0T, 0, (size_t)6400*512*2, stream);
  hipMemsetAsync(BG1T, 0, (size_t)4352*512*2, stream);

  auto tp = [&](const float* src, long row_off, long srow, bf16* dstbase, long colbase, int N, int K){
    long total = (long)N*K;
    k_tpose<<<dim3((total + 255)/256), 256, 0, stream>>>(src + row_off*srow, srow, dstbase + colbase*K, K, total);
  };
  // BXT cols: [Wx0|Wr0|Wx1|Wr1|Wx2|Wr2|pad]
  tp(wx_w[0],0,2048, BXT,0,2048,512);   tp(wr_w[0],0,64, BXT,2048,64,512);
  tp(wx_w[1],0,2048, BXT,2112,2048,512);tp(wr_w[1],0,64, BXT,4160,64,512);
  tp(wx_w[2],0,2048, BXT,4224,2048,512);tp(wr_w[2],0,64, BXT,6272,64,512);
  // BG0T cols: [Wx1.h0|Wr1.h0|Wx2.h0|Wr2.h0|Wh0|Wl0|pad]
  tp(wx_w[1],512,2048, BG0T,0,2048,512);   tp(wr_w[1],512,64, BG0T,2048,64,512);
  tp(wx_w[2],512,2048, BG0T,2112,2048,512);tp(wr_w[2],512,64, BG0T,4160,64,512);
  tp(wh_w[0],0,2048,   BG0T,4224,2048,512);tp(wl_w[0],0,64,   BG0T,6272,64,512);
  // BG1T cols: [Wx2.h1|Wr2.h1|Wh1|Wl1|pad]
  tp(wx_w[2],1024,2048, BG1T,0,2048,512);  tp(wr_w[2],1024,64, BG1T,2048,64,512);
  tp(wh_w[1],0,2048,    BG1T,2112,2048,512);tp(wl_w[1],0,64,   BG1T,4160,64,512);
  tp(wh_w[2],0,2048, BG2T,0,2048,512);
  tp(proj_w,0,512, projT,0,512,1536);

  k_bias<<<dim3(24),256,0,stream>>>(wx_b[0],wh_b[0],wx_b[1],wh_b[1],wx_b[2],wh_b[2], biasg);
  hipMemsetAsync(ubuf, 0, (size_t)4*2*BB*64*4, stream);
  hipMemsetAsync(whb1, 0, (size_t)2*SZG*4, stream);
  hipMemsetAsync(whb2, 0, (size_t)2*SZG*4, stream);
  hipMemsetAsync(cbuf, 0, (size_t)3*BB*DD*4, stream);
  hipMemsetAsync(accg, 0, (size_t)SZG*4, stream);   // slotg(0,0): E0(0)'s h-part (h(-1)=0)
  k_dinit<<<dim3((3*BB*KK + 255)/256),256,0,stream>>>(init_keys, dbuf);

  // ---- pipelined recurrence.
  // A(t) = {E0(t),E1(t-1),E2(t-2)}
  // B(t) = {X(t+5), G0(t), G1(t-1), G2(t-2), proj(t-2)} - X has no dep on A(t),
  // it fills CUs while the dependent groups' K-chains drain. Prologue: B(-2)
  // computes x-steps 0..2, B(-1) steps 3..4; x(s) written at B(s-5), slot s%8,
  // last read at A(s+2) -> slot reuse (s vs s-8) is race-free.
  for (int t = -2; t <= TT + 1; ++t) {
    // ----- A phase
    CArgs ca{}; ca.n = 0;
    auto addE = [&](int s, int l){
      CellDesc& e = ca.e[ca.n++];
      long ro = xrow(s)*XW + (long)l*2112;
      if (plan == 0) {
        e.xg = (void*)((float*)xring + ro);
        e.xr = (void*)((float*)xring + ro + 2048);
        e.xbf = 0;
      } else {
        e.xg = (void*)((bf16*)xring + ro);
        e.xr = (void*)((bf16*)xring + ro + 2048);
        e.xbf = 1;
      }
      e.gr = (l >= 1) ? slotr(s,l) : nullptr;
      e.gate = slotg(s,l);
      e.gate2 = (l==1) ? slotw1(s) : (l==2) ? slotw2(s) : nullptr;
      e.gate3 = (l==2) ? (g2b + (long)(s&1)*SZG) : nullptr;
      e.u0 = (l>=1) ? slotu(s-1,0) : nullptr;
      e.u1 = (l>=2) ? slotu(s-1,1) : nullptr;
      e.c = cbuf + (long)l*BB*DD; e.d = dbuf + (long)l*BB*KK;
      e.hout = hb(s) + (long)l*512;
    };
    if (t   >= 0 && t   < TT) addE(t,   0);
    if (t-1 >= 0 && t-1 < TT) addE(t-1, 1);
    if (t-2 >= 0 && t-2 < TT) addE(t-2, 2);
    if (ca.n)
      cell_batched<<<dim3(256, ca.n), 256, 0, stream>>>(ca, wd_w);

    // ----- B phase
    GArgs ga{}; ga.ng = 0;
    int cursor = 0;
    auto addG = [&](const bf16* A, long lda, const bf16* Bm, long ldb,
                    int mtiles, int ntiles, int order, int Kd, SegList sl){
      GDesc& g = ga.g[ga.ng++];
      g.A = A; g.lda = lda; g.B = Bm; g.ldb = ldb;
      g.mtiles = mtiles; g.ntiles = ntiles; g.tile_beg = cursor; g.order = order; g.K = Kd;
      cursor += mtiles * ntiles;
      g.segs = sl;
    };
    auto addX = [&](int s0, int nsteps){   // x-GEMM for steps [s0, s0+nsteps)
      SegList sl{}; sl.n = 6;
      if (plan == 0) {
        float* x0 = (float*)xring + xrow(s0)*XW;
        sl.s[0] = { x0,      XW,    0, 0, biasg + 0    };
        sl.s[1] = { x0+2048, XW, 2048, 0, nullptr      };
        sl.s[2] = { x0+2112, XW, 2112, 0, biasg + 2048 };
        sl.s[3] = { x0+4160, XW, 4160, 0, nullptr      };
        sl.s[4] = { x0+4224, XW, 4224, 0, biasg + 4096 };
        sl.s[5] = { x0+6272, XW, 6272, 0, nullptr      };
      } else {
        bf16* x0 = (bf16*)xring + xrow(s0)*XW;
        sl.s[0] = { x0,      XW,    0, 2, biasg + 0    };
        sl.s[1] = { x0+2048, XW, 2048, 2, nullptr      };
        sl.s[2] = { x0+2112, XW, 2112, 2, biasg + 2048 };
        sl.s[3] = { x0+4160, XW, 4160, 2, nullptr      };
        sl.s[4] = { x0+4224, XW, 4224, 2, biasg + 4096 };
        sl.s[5] = { x0+6272, XW, 6272, 2, nullptr      };
      }
      addG(xb + (long)s0*512*512, 512, BXT, 512, nsteps*8, 50, 1, 512, sl);
    };
    if (t == -2)                     addX(0, 3);
    else if (t == -1)                addX(3, 2);
    else if (t >= 0 && t + 5 < TT)   addX(t + 5, 1);
    if (t >= 0 && t < TT) {      // G0(t): h0-driven
      int s = t;
      SegList sl{}; sl.n = 7;
      sl.s[0] = { slotg(s,1),   2048,    0, 0, nullptr };
      sl.s[1] = { slotr(s,1),     64, 2048, 0, nullptr };
      sl.s[2] = { slotg(s,2),   2048, 2112, 0, nullptr };
      sl.s[3] = { slotr(s,2),     64, 4160, 0, nullptr };
      sl.s[4] = { slotg(s+1,0), 2048, 4224, 0, nullptr };  // Wh0 -> gate0(t+1)
      sl.s[5] = { slotu(s,0),     64, 6272, 0, nullptr };  // u0 = h0@Wl0
      sl.s[6] = { dump,          128, 6336, 0, nullptr };
      addG(hb(s), LDH, BG0T, 512, 8, 50, 1, 512, sl);
    }
    if (t-1 >= 0 && t-1 < TT) {  // G1(t-1): h1-driven
      int s = t-1;
      SegList sl{}; sl.n = 5;
      sl.s[0] = { g2b + (long)(s&1)*SZG, 2048, 0, 0, nullptr };  // Wx2[h1] -> gate3 ring (no RMW)
      sl.s[1] = { slotr(s,2),     64, 2048, 1, nullptr };        // Wr2[h1] += (tiny)
      sl.s[2] = { slotw1(s+1),  2048, 2112, 0, nullptr };        // Wh1*h1(s) -> whb1 ring
      sl.s[3] = { slotu(s,1),     64, 4160, 0, nullptr };        // u1 = h1@Wl1
      sl.s[4] = { dump,          128, 4224, 0, nullptr };
      addG(hb(s) + 512, LDH, BG1T, 512, 8, 34, 1, 512, sl);
    }
    if (t-2 >= 0 && t-2 <= TT-2) {  // G2(t-2): h2-driven
      int s = t-2;
      SegList sl{}; sl.n = 1;
      sl.s[0] = { slotw2(s+1), 2048, 0, 0, nullptr };      // Wh2*h2(s) -> whb2 ring
      addG(hb(s) + 1024, LDH, BG2T, 512, 8, 16, 1, 512, sl);
    }
    if (t-2 >= 0 && t-2 < TT) {  // proj(t-2): all three h layers of step s are final
      int s = t-2;
      SegList sl{}; sl.n = 1;
      sl.s[0] = { out + (long)s*512, (long)TT*512, 0, 0, proj_b };
      addG(hb(s), LDH, projT, 1536, 8, 4, 0, 1536, sl);
    }
    if (cursor) {
      ga.total = cursor; ga.chunk = (cursor + 7) / 8;
      gemm_batched<<<dim3(ga.chunk * 8), 256, 0, stream>>>(ga);
    }
  }
}

// Round 6
// 2706.452 us; speedup vs baseline: 1.3528x; 1.1074x over previous
//
#include <hip/hip_runtime.h>
#include <hip/hip_bf16.h>

typedef __hip_bfloat16 bf16;
typedef __attribute__((ext_vector_type(8))) short s16x8;
typedef __attribute__((ext_vector_type(4))) float f32x4;

// Problem constants
#define TT 55
#define BB 512
#define DD 512
#define KK 64
#define NHS 8                    // h ring slots
#define LDH ((long)NHS*1536)     // h ring row stride

typedef const __attribute__((address_space(1))) unsigned int gu32;
typedef __attribute__((address_space(3))) unsigned int lu32;
__device__ __forceinline__ void gload16(const void* g, void* l) {
  __builtin_amdgcn_global_load_lds((gu32*)g, (lu32*)l, 16, 0, 0);
}

struct Seg {
  void*  dst;          // destination base
  long   ldd;          // row stride (elements)
  int    col_begin;    // inclusive (GEMM N space), 64-aligned, sorted asc
  int    mode;         // 0 = f32 store (+bias)
  const float* bias;   // indexed by (col - col_begin), may be null
};
struct SegList { Seg s[4]; int n; };

// A operand is split into up to 4 K-parts of exactly 512 columns each
// (x slice / h slices / zero buffer). B is one stacked-transposed buffer.
struct GDesc {
  const bf16* Ap[4]; const bf16* B;
  long ldap[4], ldb;
  int mtiles, ntiles, tile_beg, K;
  SegList segs;
};
struct GArgs { GDesc g[4]; int ng; int total; int chunk; };

// ---------------- batched GEMM: C[seg] = sum_p Ap[MxK_p] * B^T[NxK], bf16, fp32 acc
// 64x128 tile, BK=64, 4 waves (2x2 of 32x64). Depth-1 double-buffered K-loop
// (48 KB LDS): issue K-step k+1's global_load_lds BEFORE waiting on k (counted
// vmcnt(6)). At 440 blocks/phase occupancy is grid-bound, so the extra LDS is
// free (r4's regression was at 1232 blocks where it halved blocks/CU).
// LDS XOR-swizzled (block p of row r holds global block p^(r&7)).
__global__ __launch_bounds__(256) void gemm_batched(GArgs args)
{
  __shared__ __align__(16) bf16 As[2][64][64];    // 2 x 8 KB
  __shared__ __align__(16) bf16 Bs[2][128][64];   // 2 x 16 KB

  // XCD-aware: bid%8 ~ XCD; each XCD gets a contiguous tile chunk.
  int tile = (int)(blockIdx.x & 7) * args.chunk + (int)(blockIdx.x >> 3);
  if (tile >= args.total) return;

  int gi = 0;
  for (int i = 1; i < args.ng; ++i) if (tile >= args.g[i].tile_beg) gi = i;
  const GDesc& g = args.g[gi];
  const int local = tile - g.tile_beg;
  const int mt = local % g.mtiles;           // mt-fast: B panel shared by consecutive tiles
  const int nt = local / g.mtiles;

  const int tid  = threadIdx.x;
  const int wave = tid >> 6, lane = tid & 63;
  const int q = lane >> 4, mm = lane & 15;
  const int s7 = mm & 7;
  const int wm = wave >> 1, wn = wave & 1;
  const long m0 = (long)mt * 64;
  const long n0 = (long)nt * 128;

  const bf16* Bb = g.B + n0 * g.ldb;
  const long ldb = g.ldb;
  const int l8 = lane >> 3;                 // row within 8-row staging group
  const int gc = ((lane & 7) ^ l8) << 3;    // swizzled global col (elements)

  const int nk = g.K >> 6;                  // K-steps (16/24/32)

  auto stage = [&](int b, int k0) {
    const int p = k0 >> 9;                  // 512-wide K-parts; 64-steps never cross
    const long ldap = g.ldap[p];
    const bf16* Abp = g.Ap[p] + m0 * ldap;
    const int ko = k0 & 511;
#pragma unroll
    for (int pp = 0; pp < 2; ++pp) {
      int r = pp*32 + wave*8;
      gload16(Abp + (long)(r + l8)*ldap + ko + gc, &As[b][r][0]);
    }
#pragma unroll
    for (int pp = 0; pp < 4; ++pp) {
      int r = pp*32 + wave*8;
      gload16(Bb + (long)(r + l8)*ldb + k0 + gc, &Bs[b][r][0]);
    }
  };

  f32x4 acc[2][4] = {};

  stage(0, 0);                              // 6 loads in flight
  for (int k = 0; k < nk; ++k) {
    const int cur = k & 1;
    if (k + 1 < nk) {
      stage(cur ^ 1, (k + 1) << 6);         // 12 in flight
      asm volatile("s_waitcnt vmcnt(6)" ::: "memory");   // k's 6 landed
    } else {
      asm volatile("s_waitcnt vmcnt(0)" ::: "memory");
    }
    __builtin_amdgcn_s_barrier();           // all waves' k-data in LDS
#pragma unroll
    for (int kk = 0; kk < 64; kk += 32) {
      const int pc = ((((kk >> 3) + q) ^ s7) << 3);  // physical col of logical kk+q*8
      s16x8 av[2], bv[4];
#pragma unroll
      for (int i = 0; i < 2; ++i) av[i] = *(const s16x8*)&As[cur][wm*32 + i*16 + mm][pc];
#pragma unroll
      for (int j = 0; j < 4; ++j) bv[j] = *(const s16x8*)&Bs[cur][wn*64 + j*16 + mm][pc];
#pragma unroll
      for (int i = 0; i < 2; ++i)
#pragma unroll
        for (int j = 0; j < 4; ++j)
          acc[i][j] = __builtin_amdgcn_mfma_f32_16x16x32_bf16(av[i], bv[j], acc[i][j], 0,0,0);
    }
    __builtin_amdgcn_s_barrier();           // buf cur free for restage at k+2
  }

  // epilogue: segment lookup per 16-col group (boundaries are 64-aligned)
#pragma unroll
  for (int j = 0; j < 4; ++j) {
    int colbase = (int)n0 + wn*64 + j*16;
    Seg sg = g.segs.s[0];
    for (int i = 1; i < g.segs.n; ++i)
      if (colbase >= g.segs.s[i].col_begin) sg = g.segs.s[i];
    int dcol = colbase + mm - sg.col_begin;
    float bv = sg.bias ? sg.bias[dcol] : 0.0f;
#pragma unroll
    for (int i = 0; i < 2; ++i) {
      f32x4 a = acc[i][j];
#pragma unroll
      for (int r = 0; r < 4; ++r) {
        long row = m0 + wm*32 + i*16 + q*4 + r;  // C/D: col=lane&15, row=q*4+reg
        ((float*)sg.dst)[row * sg.ldd + dcol] = a[r] + bv;
      }
    }
  }
}

// ---------------- batched cell update: up to 3 independent (step,layer) cells
struct CellDesc {
  const float* gate;   // fp32 ring [512][2048] - complete (bias + all parts)
  const float* gr;     // fp32 [512][64] - complete x+h parts
  const float* u0;     // may be null (ALPHA-scaled in cell)
  const float* u1;     // may be null
  float* c;            // [512][512]
  float* d;            // [512][64]
  bf16*  hout;         // row stride LDH
};
struct CArgs { CellDesc e[3]; int n; };

__device__ inline float sigm(float x){ return 1.0f/(1.0f + __expf(-x)); }
__device__ inline float ftanh(float x){ float e = __expf(2.0f*x); return 1.0f - 2.0f/(e + 1.0f); }

// 2 batch rows per block, grid (256, n).
__global__ __launch_bounds__(256) void cell_batched(CArgs a, const float* __restrict__ wd)
{
  const CellDesc e = a.e[blockIdx.y];
  const int tid = threadIdx.x;
  const int r0 = blockIdx.x * 2;
  __shared__ float dn[2][64];

  if (tid < 128) {
    int r = tid >> 6, k = tid & 63;
    long row = r0 + r;
    float gv = e.gr[row*64 + k];
    if (e.u0) gv += (1.0f/3.0f)*e.u0[row*64 + k];
    if (e.u1) gv += (1.0f/3.0f)*e.u1[row*64 + k];
    float rr = sigm(gv);
    float dv = rr * e.d[row*64 + k];
    e.d[row*64 + k] = dv;
    dn[r][k] = dv;
  }
  __syncthreads();

  float accv[2][2] = {};
#pragma unroll 4
  for (int k = 0; k < 64; ++k) {
    float w0 = wd[k*512 + tid];
    float w1 = wd[k*512 + tid + 256];
#pragma unroll
    for (int r = 0; r < 2; ++r) {
      float dv = dn[r][k];
      accv[0][r] += dv * w0;
      accv[1][r] += dv * w1;
    }
  }

#pragma unroll
  for (int half = 0; half < 2; ++half) {
    int n = tid + half*256;
#pragma unroll
    for (int r = 0; r < 2; ++r) {
      long row = r0 + r;
      const float* gg = e.gate + row*2048;
      float fv = sigm(gg[n]);
      float iv = sigm(gg[512+n]);
      float ov = sigm(gg[1024+n]);
      float cb = ftanh(gg[1536+n]);
      float cv = fv * e.c[row*512 + n] + iv * cb + ftanh(accv[half][r]);
      e.c[row*512 + n] = cv;
      e.hout[row*LDH + n] = __float2bfloat16(ov * ftanh(cv));
    }
  }
}

// ---------------- setup kernels
// transpose a 512-K-wide block of an fp32 [K x N] weight into a stacked bf16
// buffer: dst[n*drow + koff + k] = src[k*srow + n]
__global__ void k_tpose2(const float* __restrict__ src, long srow,
                         bf16* __restrict__ dst, long drow, int kcnt, long koff,
                         long total)
{
  long idx = (long)blockIdx.x * 256 + threadIdx.x;
  if (idx >= total) return;
  long n = idx / kcnt;
  long k = idx - n * kcnt;
  dst[n*drow + koff + k] = __float2bfloat16(src[k * srow + n]);
}

__global__ void k_xconv(const float* __restrict__ x, bf16* __restrict__ xb)
{
  long i = (long)blockIdx.x * 256 + threadIdx.x;
  if (i >= (long)TT*BB*512) return;
  int cc = (int)(i & 511);
  long r = i >> 9;
  int t = (int)(r / BB), b = (int)(r - (long)t*BB);
  xb[i] = __float2bfloat16(x[((long)b*TT + t)*512 + cc]);
}

__global__ void k_bias(const float* b0,const float* b1,const float* b2,
                       const float* b3,const float* b4,const float* b5,
                       float* out)
{
  int i = blockIdx.x*256 + threadIdx.x;
  if (i < 2048)      out[i] = b0[i] + b1[i];
  else if (i < 4096) out[i] = b2[i-2048] + b3[i-2048];
  else if (i < 6144) out[i] = b4[i-4096] + b5[i-4096];
}

__global__ void k_dinit(const float* __restrict__ keys, float* __restrict__ d)
{
  int i = blockIdx.x*256 + threadIdx.x;
  if (i < 3*BB*KK) d[i] = keys[i % (BB*KK)];
}

// ---------------- host
extern "C" void kernel_launch(void* const* d_in, const int* in_sizes, int n_in,
                              void* d_out, int out_size, void* d_ws, size_t ws_size,
                              hipStream_t stream)
{
  const float* inputs    = (const float*)d_in[0];
  const float* init_keys = (const float*)d_in[1];
  const float* wx_w[3] = {(const float*)d_in[2],  (const float*)d_in[8],  (const float*)d_in[14]};
  const float* wx_b[3] = {(const float*)d_in[3],  (const float*)d_in[9],  (const float*)d_in[15]};
  const float* wh_w[3] = {(const float*)d_in[4],  (const float*)d_in[10], (const float*)d_in[16]};
  const float* wh_b[3] = {(const float*)d_in[5],  (const float*)d_in[11], (const float*)d_in[17]};
  const float* wr_w[3] = {(const float*)d_in[6],  (const float*)d_in[12], (const float*)d_in[18]};
  const float* wl_w[3] = {(const float*)d_in[7],  (const float*)d_in[13], (const float*)d_in[19]};
  const float* wd_w   = (const float*)d_in[20];
  const float* proj_w = (const float*)d_in[21];
  const float* proj_b = (const float*)d_in[22];
  float* out = (float*)d_out;

  char* wsp = (char*)d_ws;
  size_t used = 0;
  auto alloc = [&](size_t bytes) {
    char* p = wsp + used;
    used += (bytes + 255) & ~(size_t)255;
    return p;
  };
  bf16* xb    = (bf16*)alloc((size_t)TT*BB*512*2);       // [t][b][c]
  bf16* WL0T  = (bf16*)alloc((size_t)2176*1024*2);       // [gate0|gr0|u0] x [x;h0]
  bf16* WL1T  = (bf16*)alloc((size_t)2176*1536*2);       // [gate1|gr1|u1] x [x;h0;h1]
  bf16* WL2T  = (bf16*)alloc((size_t)2176*2048*2);       // [gate2|gr2|pad] x [x;h0;h1;h2]
  bf16* projT = (bf16*)alloc((size_t)512*1536*2);
  bf16* HallR = (bf16*)alloc((size_t)BB*NHS*1536*2);     // h ring [b][slot][3*512]
  bf16* hz    = (bf16*)alloc((size_t)BB*512*2);          // zero h (t=-1 operands)
  float* accg = (float*)alloc((size_t)4*3*BB*2048*4);    // gate rings [slot][l][b][2048]
  float* accr = (float*)alloc((size_t)4*3*BB*64*4);      // gr rings
  float* ubuf = (float*)alloc((size_t)4*2*BB*64*4);      // u rings [slot][j][b][64]
  float* cbuf = (float*)alloc((size_t)3*BB*DD*4);
  float* dbuf = (float*)alloc((size_t)3*BB*KK*4);
  float* biasg= (float*)alloc((size_t)3*2048*4);
  float* dump = (float*)alloc((size_t)BB*64*4);          // pad-column sink
  if (used > ws_size) return;

  const long SZG = (long)BB*2048;
  const long SZR = (long)BB*64;

  auto slotg = [&](int s, int l){ return accg + (long)((s&3)*3+l)*SZG; };
  auto slotr = [&](int s, int l){ return accr + (long)((s&3)*3+l)*SZR; };
  auto slotu = [&](int s, int j){ return ubuf + (long)((s&3)*2+j)*SZR; };
  auto hb    = [&](int s){ return HallR + (long)(s % NHS)*1536; };

  // ---- setup
  {
    long tot = (long)TT*BB*512;
    k_xconv<<<dim3((tot + 255)/256), 256, 0, stream>>>(inputs, xb);
  }
  hipMemsetAsync(WL0T, 0, (size_t)2176*1024*2, stream);
  hipMemsetAsync(WL1T, 0, (size_t)2176*1536*2, stream);
  hipMemsetAsync(WL2T, 0, (size_t)2176*2048*2, stream);
  hipMemsetAsync(hz,   0, (size_t)BB*512*2, stream);
  hipMemsetAsync(cbuf, 0, (size_t)3*BB*DD*4, stream);

  auto tp2 = [&](const float* src, long kOffSrc, long srow,
                 bf16* dst, long colbase, long drow, long koff, int N){
    long total = (long)N*512;
    k_tpose2<<<dim3((total + 255)/256), 256, 0, stream>>>(
        src + kOffSrc*srow, srow, dst + colbase*drow, drow, 512, koff, total);
  };
  // WL0T (drow=1024, K=[x(512);h0(512)]): cols [gate0 2048 | gr0 64 | u0 64]
  tp2(wx_w[0],0,2048, WL0T,0,1024,0,2048);
  tp2(wh_w[0],0,2048, WL0T,0,1024,512,2048);
  tp2(wr_w[0],0,64,   WL0T,2048,1024,0,64);
  tp2(wl_w[0],0,64,   WL0T,2112,1024,512,64);
  // WL1T (drow=1536, K=[x;h0;h1]): cols [gate1 2048 | gr1 64 | u1 64]
  tp2(wx_w[1],0,2048,   WL1T,0,1536,0,2048);
  tp2(wx_w[1],512,2048, WL1T,0,1536,512,2048);
  tp2(wh_w[1],0,2048,   WL1T,0,1536,1024,2048);
  tp2(wr_w[1],0,64,     WL1T,2048,1536,0,64);
  tp2(wr_w[1],512,64,   WL1T,2048,1536,512,64);
  tp2(wl_w[1],0,64,     WL1T,2112,1536,1024,64);
  // WL2T (drow=2048, K=[x;h0;h1;h2]): cols [gate2 2048 | gr2 64 | pad 64]
  tp2(wx_w[2],0,2048,    WL2T,0,2048,0,2048);
  tp2(wx_w[2],512,2048,  WL2T,0,2048,512,2048);
  tp2(wx_w[2],1024,2048, WL2T,0,2048,1024,2048);
  tp2(wh_w[2],0,2048,    WL2T,0,2048,1536,2048);
  tp2(wr_w[2],0,64,      WL2T,2048,2048,0,64);
  tp2(wr_w[2],512,64,    WL2T,2048,2048,512,64);
  tp2(wr_w[2],1024,64,   WL2T,2048,2048,1024,64);
  // projT (drow=1536, K=[h0;h1;h2])
  {
    long total = (long)512*1536;
    k_tpose2<<<dim3((total + 255)/256), 256, 0, stream>>>(
        proj_w, 512, projT, 1536, 1536, 0, total);
  }

  k_bias<<<dim3(24),256,0,stream>>>(wx_b[0],wh_b[0],wx_b[1],wh_b[1],wx_b[2],wh_b[2], biasg);
  k_dinit<<<dim3((3*BB*KK + 255)/256),256,0,stream>>>(init_keys, dbuf);

  // ---- pipelined recurrence. Phase t:
  //   A(t): cells {E0(t), E1(t-1), E2(t-2)}
  //   B(t): L0 -> gate0/gr0(t+1), u0(t)   A=[x(t+1); h0(t)]        K=1024
  //         L1 -> gate1/gr1(t),   u1(t-1) A=[x(t); h0(t); h1(t-1)] K=1536
  //         L2 -> gate2/gr2(t-1)          A=[x(t-1); h0..h1(t-1); h2(t-2)] K=2048
  //         proj(t-2)                     A=[h(t-2)]               K=1536
  // All h operands are produced by cells in the same or earlier phases (checked);
  // h(-1)=hz (zeros) reproduces the zero initial state, and L0(-1)/L1(0) write
  // the zero u0(-1)/u1(-1) slots the first cells read.
  for (int t = -1; t <= TT + 1; ++t) {
    // ----- A phase
    CArgs ca{}; ca.n = 0;
    auto addE = [&](int s, int l){
      CellDesc& e = ca.e[ca.n++];
      e.gate = slotg(s,l);
      e.gr   = slotr(s,l);
      e.u0 = (l>=1) ? slotu(s-1,0) : nullptr;
      e.u1 = (l>=2) ? slotu(s-1,1) : nullptr;
      e.c = cbuf + (long)l*BB*DD; e.d = dbuf + (long)l*BB*KK;
      e.hout = hb(s) + (long)l*512;
    };
    if (t   >= 0 && t   < TT) addE(t,   0);
    if (t-1 >= 0 && t-1 < TT) addE(t-1, 1);
    if (t-2 >= 0 && t-2 < TT) addE(t-2, 2);
    if (ca.n)
      cell_batched<<<dim3(256, ca.n), 256, 0, stream>>>(ca, wd_w);

    // ----- B phase
    GArgs ga{}; ga.ng = 0;
    int cursor = 0;
    auto addG = [&](const bf16* B, long ldb, int ntiles, int Kd, SegList sl,
                    const bf16* a0, long l0, const bf16* a1, long l1,
                    const bf16* a2, long l2, const bf16* a3, long l3){
      GDesc& g = ga.g[ga.ng++];
      g.Ap[0]=a0; g.Ap[1]=a1; g.Ap[2]=a2; g.Ap[3]=a3;
      g.ldap[0]=l0; g.ldap[1]=l1; g.ldap[2]=l2; g.ldap[3]=l3;
      g.B = B; g.ldb = ldb;
      g.mtiles = 8; g.ntiles = ntiles; g.tile_beg = cursor; g.K = Kd;
      cursor += 8 * ntiles;
      g.segs = sl;
    };
    if (t >= -1 && t <= TT-2) {        // L0 -> step t+1
      SegList sl{}; sl.n = 3;
      sl.s[0] = { slotg(t+1,0), 2048,    0, 0, biasg + 0 };
      sl.s[1] = { slotr(t+1,0),   64, 2048, 0, nullptr   };
      sl.s[2] = { slotu(t,0),     64, 2112, 0, nullptr   };
      addG(WL0T, 1024, 17, 1024, sl,
           xb + (long)(t+1)*BB*512, 512,
           (t>=0)? hb(t) : hz, (t>=0)? LDH : 512,
           nullptr,0, nullptr,0);
    }
    if (t >= 0 && t <= TT-1) {         // L1 -> step t
      SegList sl{}; sl.n = 3;
      sl.s[0] = { slotg(t,1),   2048,    0, 0, biasg + 2048 };
      sl.s[1] = { slotr(t,1),     64, 2048, 0, nullptr      };
      sl.s[2] = { slotu(t-1,1),   64, 2112, 0, nullptr      };
      addG(WL1T, 1536, 17, 1536, sl,
           xb + (long)t*BB*512, 512,
           hb(t), LDH,
           (t>=1)? hb(t-1)+512 : hz, (t>=1)? LDH : 512,
           nullptr,0);
    }
    if (t >= 1 && t <= TT) {           // L2 -> step s=t-1
      int s = t-1;
      SegList sl{}; sl.n = 3;
      sl.s[0] = { slotg(s,2), 2048,    0, 0, biasg + 4096 };
      sl.s[1] = { slotr(s,2),   64, 2048, 0, nullptr      };
      sl.s[2] = { dump,         64, 2112, 0, nullptr      };
      addG(WL2T, 2048, 17, 2048, sl,
           xb + (long)s*BB*512, 512,
           hb(s), LDH,
           hb(s)+512, LDH,
           (s>=1)? hb(s-1)+1024 : hz, (s>=1)? LDH : 512);
    }
    if (t-2 >= 0 && t-2 < TT) {        // proj(t-2)
      int s = t-2;
      SegList sl{}; sl.n = 1;
      sl.s[0] = { out + (long)s*512, (long)TT*512, 0, 0, proj_b };
      addG(projT, 1536, 4, 1536, sl,
           hb(s), LDH, hb(s)+512, LDH, hb(s)+1024, LDH, nullptr,0);
    }
    if (cursor) {
      ga.total = cursor; ga.chunk = (cursor + 7) / 8;
      gemm_batched<<<dim3(ga.chunk * 8), 256, 0, stream>>>(ga);
    }
  }
}

// Round 7
// 2500.840 us; speedup vs baseline: 1.4640x; 1.0822x over previous
//
#include <hip/hip_runtime.h>
#include <hip/hip_bf16.h>

typedef __hip_bfloat16 bf16;
typedef __attribute__((ext_vector_type(8))) short s16x8;
typedef __attribute__((ext_vector_type(4))) float f32x4;

// Problem constants
#define TT 55
#define BB 512
#define DD 512
#define KK 64
#define NHS 8                    // h ring slots
#define LDH ((long)NHS*1536)     // h ring row stride

typedef const __attribute__((address_space(1))) unsigned int gu32;
typedef __attribute__((address_space(3))) unsigned int lu32;
__device__ __forceinline__ void gload16(const void* g, void* l) {
  __builtin_amdgcn_global_load_lds((gu32*)g, (lu32*)l, 16, 0, 0);
}

struct Seg {
  void*  dst;          // destination base
  long   ldd;          // row stride (elements)
  int    col_begin;    // inclusive (GEMM N space), 64-aligned, sorted asc
  int    mode;         // 0 = f32 store (+bias)
  const float* bias;   // indexed by (col - col_begin), may be null
};
struct SegList { Seg s[4]; int n; };

// A operand is split into up to 4 K-parts of exactly 512 columns each
// (x slice / h slices / zero buffer). B is one stacked-transposed buffer.
struct GDesc {
  const bf16* Ap[4]; const bf16* B;
  long ldap[4], ldb;
  int mtiles, ntiles, tile_beg, K;
  SegList segs;
};
struct GArgs { GDesc g[4]; int ng; int total; int chunk; };

// ---------------- batched GEMM: C[seg] = sum_p Ap[MxK_p] * B^T[NxK], bf16, fp32 acc
// 64x64 tile, BK=64, 4 waves (2x2 of 32x32). N-split from 64x128 doubles the
// grid (880 blocks, 3.4/CU) - the phases are TLP-starved, not BW-bound, so 2x
// concurrency beats the ~34% A-re-read cost. Depth-1 double-buffered K-loop
// (32 KB LDS, still grid-bound so dbuf is free): issue k+1's global_load_lds
// before waiting on k (counted vmcnt(4)).
// LDS XOR-swizzled (block p of row r holds global block p^(r&7)).
__global__ __launch_bounds__(256) void gemm_batched(GArgs args)
{
  __shared__ __align__(16) bf16 As[2][64][64];    // 2 x 8 KB
  __shared__ __align__(16) bf16 Bs[2][64][64];    // 2 x 8 KB

  // XCD-aware: bid%8 ~ XCD; each XCD gets a contiguous tile chunk.
  int tile = (int)(blockIdx.x & 7) * args.chunk + (int)(blockIdx.x >> 3);
  if (tile >= args.total) return;

  int gi = 0;
  for (int i = 1; i < args.ng; ++i) if (tile >= args.g[i].tile_beg) gi = i;
  const GDesc& g = args.g[gi];
  const int local = tile - g.tile_beg;
  const int mt = local % g.mtiles;           // mt-fast: B panel shared by consecutive tiles
  const int nt = local / g.mtiles;

  const int tid  = threadIdx.x;
  const int wave = tid >> 6, lane = tid & 63;
  const int q = lane >> 4, mm = lane & 15;
  const int s7 = mm & 7;
  const int wm = wave >> 1, wn = wave & 1;
  const long m0 = (long)mt * 64;
  const long n0 = (long)nt * 64;

  const bf16* Bb = g.B + n0 * g.ldb;
  const long ldb = g.ldb;
  const int l8 = lane >> 3;                 // row within 8-row staging group
  const int gc = ((lane & 7) ^ l8) << 3;    // swizzled global col (elements)

  const int nk = g.K >> 6;                  // K-steps (16/24/32)

  auto stage = [&](int b, int k0) {
    const int p = k0 >> 9;                  // 512-wide K-parts; 64-steps never cross
    const long ldap = g.ldap[p];
    const bf16* Abp = g.Ap[p] + m0 * ldap;
    const int ko = k0 & 511;
#pragma unroll
    for (int pp = 0; pp < 2; ++pp) {
      int r = pp*32 + wave*8;
      gload16(Abp + (long)(r + l8)*ldap + ko + gc, &As[b][r][0]);
    }
#pragma unroll
    for (int pp = 0; pp < 2; ++pp) {
      int r = pp*32 + wave*8;
      gload16(Bb + (long)(r + l8)*ldb + k0 + gc, &Bs[b][r][0]);
    }
  };

  f32x4 acc[2][2] = {};

  stage(0, 0);                              // 4 loads in flight
  for (int k = 0; k < nk; ++k) {
    const int cur = k & 1;
    if (k + 1 < nk) {
      stage(cur ^ 1, (k + 1) << 6);         // 8 in flight
      asm volatile("s_waitcnt vmcnt(4)" ::: "memory");   // k's 4 landed
    } else {
      asm volatile("s_waitcnt vmcnt(0)" ::: "memory");
    }
    __builtin_amdgcn_s_barrier();           // all waves' k-data in LDS
#pragma unroll
    for (int kk = 0; kk < 64; kk += 32) {
      const int pc = ((((kk >> 3) + q) ^ s7) << 3);  // physical col of logical kk+q*8
      s16x8 av[2], bv[2];
#pragma unroll
      for (int i = 0; i < 2; ++i) av[i] = *(const s16x8*)&As[cur][wm*32 + i*16 + mm][pc];
#pragma unroll
      for (int j = 0; j < 2; ++j) bv[j] = *(const s16x8*)&Bs[cur][wn*32 + j*16 + mm][pc];
#pragma unroll
      for (int i = 0; i < 2; ++i)
#pragma unroll
        for (int j = 0; j < 2; ++j)
          acc[i][j] = __builtin_amdgcn_mfma_f32_16x16x32_bf16(av[i], bv[j], acc[i][j], 0,0,0);
    }
    __builtin_amdgcn_s_barrier();           // buf cur free for restage at k+2
  }

  // epilogue: segment lookup per 16-col group (boundaries are 64-aligned)
#pragma unroll
  for (int j = 0; j < 2; ++j) {
    int colbase = (int)n0 + wn*32 + j*16;
    Seg sg = g.segs.s[0];
    for (int i = 1; i < g.segs.n; ++i)
      if (colbase >= g.segs.s[i].col_begin) sg = g.segs.s[i];
    int dcol = colbase + mm - sg.col_begin;
    float bv = sg.bias ? sg.bias[dcol] : 0.0f;
#pragma unroll
    for (int i = 0; i < 2; ++i) {
      f32x4 a = acc[i][j];
#pragma unroll
      for (int r = 0; r < 4; ++r) {
        long row = m0 + wm*32 + i*16 + q*4 + r;  // C/D: col=lane&15, row=q*4+reg
        ((float*)sg.dst)[row * sg.ldd + dcol] = a[r] + bv;
      }
    }
  }
}

// ---------------- batched cell update: up to 3 independent (step,layer) cells
struct CellDesc {
  const float* gate;   // fp32 ring [512][2048] - complete (bias + all parts)
  const float* gr;     // fp32 [512][64] - complete x+h parts
  const float* u0;     // may be null (ALPHA-scaled in cell)
  const float* u1;     // may be null
  float* c;            // [512][512]
  float* d;            // [512][64]
  bf16*  hout;         // row stride LDH
};
struct CArgs { CellDesc e[3]; int n; };

__device__ inline float sigm(float x){ return 1.0f/(1.0f + __expf(-x)); }
__device__ inline float ftanh(float x){ float e = __expf(2.0f*x); return 1.0f - 2.0f/(e + 1.0f); }

// 2 batch rows per block, grid (256, n).
__global__ __launch_bounds__(256) void cell_batched(CArgs a, const float* __restrict__ wd)
{
  const CellDesc e = a.e[blockIdx.y];
  const int tid = threadIdx.x;
  const int r0 = blockIdx.x * 2;
  __shared__ float dn[2][64];

  if (tid < 128) {
    int r = tid >> 6, k = tid & 63;
    long row = r0 + r;
    float gv = e.gr[row*64 + k];
    if (e.u0) gv += (1.0f/3.0f)*e.u0[row*64 + k];
    if (e.u1) gv += (1.0f/3.0f)*e.u1[row*64 + k];
    float rr = sigm(gv);
    float dv = rr * e.d[row*64 + k];
    e.d[row*64 + k] = dv;
    dn[r][k] = dv;
  }
  __syncthreads();

  float accv[2][2] = {};
#pragma unroll 4
  for (int k = 0; k < 64; ++k) {
    float w0 = wd[k*512 + tid];
    float w1 = wd[k*512 + tid + 256];
#pragma unroll
    for (int r = 0; r < 2; ++r) {
      float dv = dn[r][k];
      accv[0][r] += dv * w0;
      accv[1][r] += dv * w1;
    }
  }

#pragma unroll
  for (int half = 0; half < 2; ++half) {
    int n = tid + half*256;
#pragma unroll
    for (int r = 0; r < 2; ++r) {
      long row = r0 + r;
      const float* gg = e.gate + row*2048;
      float fv = sigm(gg[n]);
      float iv = sigm(gg[512+n]);
      float ov = sigm(gg[1024+n]);
      float cb = ftanh(gg[1536+n]);
      float cv = fv * e.c[row*512 + n] + iv * cb + ftanh(accv[half][r]);
      e.c[row*512 + n] = cv;
      e.hout[row*LDH + n] = __float2bfloat16(ov * ftanh(cv));
    }
  }
}

// ---------------- setup kernels
// transpose a 512-K-wide block of an fp32 [K x N] weight into a stacked bf16
// buffer: dst[n*drow + koff + k] = src[k*srow + n]
__global__ void k_tpose2(const float* __restrict__ src, long srow,
                         bf16* __restrict__ dst, long drow, int kcnt, long koff,
                         long total)
{
  long idx = (long)blockIdx.x * 256 + threadIdx.x;
  if (idx >= total) return;
  long n = idx / kcnt;
  long k = idx - n * kcnt;
  dst[n*drow + koff + k] = __float2bfloat16(src[k * srow + n]);
}

__global__ void k_xconv(const float* __restrict__ x, bf16* __restrict__ xb)
{
  long i = (long)blockIdx.x * 256 + threadIdx.x;
  if (i >= (long)TT*BB*512) return;
  int cc = (int)(i & 511);
  long r = i >> 9;
  int t = (int)(r / BB), b = (int)(r - (long)t*BB);
  xb[i] = __float2bfloat16(x[((long)b*TT + t)*512 + cc]);
}

__global__ void k_bias(const float* b0,const float* b1,const float* b2,
                       const float* b3,const float* b4,const float* b5,
                       float* out)
{
  int i = blockIdx.x*256 + threadIdx.x;
  if (i < 2048)      out[i] = b0[i] + b1[i];
  else if (i < 4096) out[i] = b2[i-2048] + b3[i-2048];
  else if (i < 6144) out[i] = b4[i-4096] + b5[i-4096];
}

__global__ void k_dinit(const float* __restrict__ keys, float* __restrict__ d)
{
  int i = blockIdx.x*256 + threadIdx.x;
  if (i < 3*BB*KK) d[i] = keys[i % (BB*KK)];
}

// ---------------- host
extern "C" void kernel_launch(void* const* d_in, const int* in_sizes, int n_in,
                              void* d_out, int out_size, void* d_ws, size_t ws_size,
                              hipStream_t stream)
{
  const float* inputs    = (const float*)d_in[0];
  const float* init_keys = (const float*)d_in[1];
  const float* wx_w[3] = {(const float*)d_in[2],  (const float*)d_in[8],  (const float*)d_in[14]};
  const float* wx_b[3] = {(const float*)d_in[3],  (const float*)d_in[9],  (const float*)d_in[15]};
  const float* wh_w[3] = {(const float*)d_in[4],  (const float*)d_in[10], (const float*)d_in[16]};
  const float* wh_b[3] = {(const float*)d_in[5],  (const float*)d_in[11], (const float*)d_in[17]};
  const float* wr_w[3] = {(const float*)d_in[6],  (const float*)d_in[12], (const float*)d_in[18]};
  const float* wl_w[3] = {(const float*)d_in[7],  (const float*)d_in[13], (const float*)d_in[19]};
  const float* wd_w   = (const float*)d_in[20];
  const float* proj_w = (const float*)d_in[21];
  const float* proj_b = (const float*)d_in[22];
  float* out = (float*)d_out;

  char* wsp = (char*)d_ws;
  size_t used = 0;
  auto alloc = [&](size_t bytes) {
    char* p = wsp + used;
    used += (bytes + 255) & ~(size_t)255;
    return p;
  };
  bf16* xb    = (bf16*)alloc((size_t)TT*BB*512*2);       // [t][b][c]
  bf16* WL0T  = (bf16*)alloc((size_t)2176*1024*2);       // [gate0|gr0|u0] x [x;h0]
  bf16* WL1T  = (bf16*)alloc((size_t)2176*1536*2);       // [gate1|gr1|u1] x [x;h0;h1]
  bf16* WL2T  = (bf16*)alloc((size_t)2176*2048*2);       // [gate2|gr2|pad] x [x;h0;h1;h2]
  bf16* projT = (bf16*)alloc((size_t)512*1536*2);
  bf16* HallR = (bf16*)alloc((size_t)BB*NHS*1536*2);     // h ring [b][slot][3*512]
  bf16* hz    = (bf16*)alloc((size_t)BB*512*2);          // zero h (t=-1 operands)
  float* accg = (float*)alloc((size_t)4*3*BB*2048*4);    // gate rings [slot][l][b][2048]
  float* accr = (float*)alloc((size_t)4*3*BB*64*4);      // gr rings
  float* ubuf = (float*)alloc((size_t)4*2*BB*64*4);      // u rings [slot][j][b][64]
  float* cbuf = (float*)alloc((size_t)3*BB*DD*4);
  float* dbuf = (float*)alloc((size_t)3*BB*KK*4);
  float* biasg= (float*)alloc((size_t)3*2048*4);
  float* dump = (float*)alloc((size_t)BB*64*4);          // pad-column sink
  if (used > ws_size) return;

  const long SZG = (long)BB*2048;
  const long SZR = (long)BB*64;

  auto slotg = [&](int s, int l){ return accg + (long)((s&3)*3+l)*SZG; };
  auto slotr = [&](int s, int l){ return accr + (long)((s&3)*3+l)*SZR; };
  auto slotu = [&](int s, int j){ return ubuf + (long)((s&3)*2+j)*SZR; };
  auto hb    = [&](int s){ return HallR + (long)(s % NHS)*1536; };

  // ---- setup
  {
    long tot = (long)TT*BB*512;
    k_xconv<<<dim3((tot + 255)/256), 256, 0, stream>>>(inputs, xb);
  }
  hipMemsetAsync(WL0T, 0, (size_t)2176*1024*2, stream);
  hipMemsetAsync(WL1T, 0, (size_t)2176*1536*2, stream);
  hipMemsetAsync(WL2T, 0, (size_t)2176*2048*2, stream);
  hipMemsetAsync(hz,   0, (size_t)BB*512*2, stream);
  hipMemsetAsync(cbuf, 0, (size_t)3*BB*DD*4, stream);

  auto tp2 = [&](const float* src, long kOffSrc, long srow,
                 bf16* dst, long colbase, long drow, long koff, int N){
    long total = (long)N*512;
    k_tpose2<<<dim3((total + 255)/256), 256, 0, stream>>>(
        src + kOffSrc*srow, srow, dst + colbase*drow, drow, 512, koff, total);
  };
  // WL0T (drow=1024, K=[x(512);h0(512)]): cols [gate0 2048 | gr0 64 | u0 64]
  tp2(wx_w[0],0,2048, WL0T,0,1024,0,2048);
  tp2(wh_w[0],0,2048, WL0T,0,1024,512,2048);
  tp2(wr_w[0],0,64,   WL0T,2048,1024,0,64);
  tp2(wl_w[0],0,64,   WL0T,2112,1024,512,64);
  // WL1T (drow=1536, K=[x;h0;h1]): cols [gate1 2048 | gr1 64 | u1 64]
  tp2(wx_w[1],0,2048,   WL1T,0,1536,0,2048);
  tp2(wx_w[1],512,2048, WL1T,0,1536,512,2048);
  tp2(wh_w[1],0,2048,   WL1T,0,1536,1024,2048);
  tp2(wr_w[1],0,64,     WL1T,2048,1536,0,64);
  tp2(wr_w[1],512,64,   WL1T,2048,1536,512,64);
  tp2(wl_w[1],0,64,     WL1T,2112,1536,1024,64);
  // WL2T (drow=2048, K=[x;h0;h1;h2]): cols [gate2 2048 | gr2 64 | pad 64]
  tp2(wx_w[2],0,2048,    WL2T,0,2048,0,2048);
  tp2(wx_w[2],512,2048,  WL2T,0,2048,512,2048);
  tp2(wx_w[2],1024,2048, WL2T,0,2048,1024,2048);
  tp2(wh_w[2],0,2048,    WL2T,0,2048,1536,2048);
  tp2(wr_w[2],0,64,      WL2T,2048,2048,0,64);
  tp2(wr_w[2],512,64,    WL2T,2048,2048,512,64);
  tp2(wr_w[2],1024,64,   WL2T,2048,2048,1024,64);
  // projT (drow=1536, K=[h0;h1;h2])
  {
    long total = (long)512*1536;
    k_tpose2<<<dim3((total + 255)/256), 256, 0, stream>>>(
        proj_w, 512, projT, 1536, 1536, 0, total);
  }

  k_bias<<<dim3(24),256,0,stream>>>(wx_b[0],wh_b[0],wx_b[1],wh_b[1],wx_b[2],wh_b[2], biasg);
  k_dinit<<<dim3((3*BB*KK + 255)/256),256,0,stream>>>(init_keys, dbuf);

  // ---- pipelined recurrence. Phase t:
  //   A(t): cells {E0(t), E1(t-1), E2(t-2)}
  //   B(t): L0 -> gate0/gr0(t+1), u0(t)   A=[x(t+1); h0(t)]        K=1024
  //         L1 -> gate1/gr1(t),   u1(t-1) A=[x(t); h0(t); h1(t-1)] K=1536
  //         L2 -> gate2/gr2(t-1)          A=[x(t-1); h0..h1(t-1); h2(t-2)] K=2048
  //         proj(t-2)                     A=[h(t-2)]               K=1536
  // h(-1)=hz (zeros) reproduces the zero initial state; L0(-1)/L1(0) write the
  // zero u0(-1)/u1(-1) slots the first cells read.
  for (int t = -1; t <= TT + 1; ++t) {
    // ----- A phase
    CArgs ca{}; ca.n = 0;
    auto addE = [&](int s, int l){
      CellDesc& e = ca.e[ca.n++];
      e.gate = slotg(s,l);
      e.gr   = slotr(s,l);
      e.u0 = (l>=1) ? slotu(s-1,0) : nullptr;
      e.u1 = (l>=2) ? slotu(s-1,1) : nullptr;
      e.c = cbuf + (long)l*BB*DD; e.d = dbuf + (long)l*BB*KK;
      e.hout = hb(s) + (long)l*512;
    };
    if (t   >= 0 && t   < TT) addE(t,   0);
    if (t-1 >= 0 && t-1 < TT) addE(t-1, 1);
    if (t-2 >= 0 && t-2 < TT) addE(t-2, 2);
    if (ca.n)
      cell_batched<<<dim3(256, ca.n), 256, 0, stream>>>(ca, wd_w);

    // ----- B phase
    GArgs ga{}; ga.ng = 0;
    int cursor = 0;
    auto addG = [&](const bf16* B, long ldb, int ntiles, int Kd, SegList sl,
                    const bf16* a0, long l0, const bf16* a1, long l1,
                    const bf16* a2, long l2, const bf16* a3, long l3){
      GDesc& g = ga.g[ga.ng++];
      g.Ap[0]=a0; g.Ap[1]=a1; g.Ap[2]=a2; g.Ap[3]=a3;
      g.ldap[0]=l0; g.ldap[1]=l1; g.ldap[2]=l2; g.ldap[3]=l3;
      g.B = B; g.ldb = ldb;
      g.mtiles = 8; g.ntiles = ntiles; g.tile_beg = cursor; g.K = Kd;
      cursor += 8 * ntiles;
      g.segs = sl;
    };
    if (t >= -1 && t <= TT-2) {        // L0 -> step t+1
      SegList sl{}; sl.n = 3;
      sl.s[0] = { slotg(t+1,0), 2048,    0, 0, biasg + 0 };
      sl.s[1] = { slotr(t+1,0),   64, 2048, 0, nullptr   };
      sl.s[2] = { slotu(t,0),     64, 2112, 0, nullptr   };
      addG(WL0T, 1024, 34, 1024, sl,
           xb + (long)(t+1)*BB*512, 512,
           (t>=0)? hb(t) : hz, (t>=0)? LDH : 512,
           nullptr,0, nullptr,0);
    }
    if (t >= 0 && t <= TT-1) {         // L1 -> step t
      SegList sl{}; sl.n = 3;
      sl.s[0] = { slotg(t,1),   2048,    0, 0, biasg + 2048 };
      sl.s[1] = { slotr(t,1),     64, 2048, 0, nullptr      };
      sl.s[2] = { slotu(t-1,1),   64, 2112, 0, nullptr      };
      addG(WL1T, 1536, 34, 1536, sl,
           xb + (long)t*BB*512, 512,
           hb(t), LDH,
           (t>=1)? hb(t-1)+512 : hz, (t>=1)? LDH : 512,
           nullptr,0);
    }
    if (t >= 1 && t <= TT) {           // L2 -> step s=t-1
      int s = t-1;
      SegList sl{}; sl.n = 3;
      sl.s[0] = { slotg(s,2), 2048,    0, 0, biasg + 4096 };
      sl.s[1] = { slotr(s,2),   64, 2048, 0, nullptr      };
      sl.s[2] = { dump,         64, 2112, 0, nullptr      };
      addG(WL2T, 2048, 34, 2048, sl,
           xb + (long)s*BB*512, 512,
           hb(s), LDH,
           hb(s)+512, LDH,
           (s>=1)? hb(s-1)+1024 : hz, (s>=1)? LDH : 512);
    }
    if (t-2 >= 0 && t-2 < TT) {        // proj(t-2)
      int s = t-2;
      SegList sl{}; sl.n = 1;
      sl.s[0] = { out + (long)s*512, (long)TT*512, 0, 0, proj_b };
      addG(projT, 1536, 8, 1536, sl,
           hb(s), LDH, hb(s)+512, LDH, hb(s)+1024, LDH, nullptr,0);
    }
    if (cursor) {
      ga.total = cursor; ga.chunk = (cursor + 7) / 8;
      gemm_batched<<<dim3(ga.chunk * 8), 256, 0, stream>>>(ga);
    }
  }
}